// Round 1
// baseline (2757.543 us; speedup 1.0000x reference)
//
#include <hip/hip_runtime.h>
#include <hip/hip_bf16.h>

#define H 256
#define TYPE_DIM 64
#define EIN (2*H + TYPE_DIM)   // 576
#define N_ENTS 100000
#define N_EDGES 200000
#define EPB 32                  // edges per block (MFMA M=32)
#define NPB 8                   // nodes per block (node kernel, unchanged)
#define KE 576                  // K of edge GEMM
#define LDE 584                 // padded LDS row (bf16 elems): +8 keeps b128 reads at the 8-alias floor
#define LDF 260                 // padded f32 row for epilogue buffer

typedef __hip_bfloat16 bf16;
typedef short bf16x8 __attribute__((ext_vector_type(8)));  // MFMA a/b frag (8 bf16 in 4 VGPRs)
typedef float f32x4 __attribute__((ext_vector_type(4)));   // MFMA acc frag

__device__ __forceinline__ float b2f(bf16 x) { return __bfloat162float(x); }

// f32 -> bf16 bits, round-to-nearest-even (matches __float2bfloat16 for finite inputs)
__device__ __forceinline__ unsigned short f2b(float f) {
    union { float f; unsigned int u; } v; v.f = f;
    unsigned int u = v.u;
    return (unsigned short)((u + 0x7FFFu + ((u >> 16) & 1u)) >> 16);
}

// ---------------- W_ih/W_hh transpose (768x256 f32 -> 256x768 bf16) --------
__global__ void transpose_kernel(const float* __restrict__ Wih,
                                 const float* __restrict__ Whh,
                                 bf16* __restrict__ WTih,
                                 bf16* __restrict__ WThh) {
    int j = blockIdx.x;      // 0..767 (row of W)
    int k = threadIdx.x;     // 0..255 (col of W)
    float a = Wih[j * H + k];
    float b = Whh[j * H + k];
    WTih[k * 768 + j] = __float2bfloat16(a);
    WThh[k * 768 + j] = __float2bfloat16(b);
}

// ---------------- W_edge -> col-major bf16 (WE[c][k], row len 576) ---------
__global__ void transpose_we(const float* __restrict__ W,
                             unsigned short* __restrict__ WE) {
    int c = blockIdx.x;                    // 0..255 output col of the GEMM
    for (int j = threadIdx.x; j < KE; j += 256)
        WE[(size_t)c * KE + j] = f2b(W[(size_t)j * H + c]);
}

// ---------------- edge MLP via MFMA + scatter-add --------------------------
// Block: 256 thr (4 waves), 32 edges. Wave w owns output cols [w*64, w*64+64).
// A (LDS): ein[32][584] bf16, row = gathered [src | dst | type] features.
// B (global, L2-resident): WE[col*576 + k] bf16 — 8 contiguous k per frag = 1 dwordx4.
__global__ __launch_bounds__(256) void edge_mfma(
    const float* __restrict__ node_emb, const float* __restrict__ type_emb,
    const unsigned short* __restrict__ WE,
    const float* __restrict__ b_edge,
    const float* __restrict__ ln_g, const float* __restrict__ ln_b,
    const int* __restrict__ src, const int* __restrict__ dst,
    const int* __restrict__ et,
    float* __restrict__ agg,            // f32 accumulator (= d_out)
    unsigned int* __restrict__ cntw) {  // u8-packed counts, 4 per word
    __shared__ __align__(16) unsigned short ein[EPB * LDE];  // 37376 B, reused as f32 fout
    __shared__ int sidx[EPB], didx[EPB], tidx[EPB];

    const int tid = threadIdx.x;
    const int e0 = blockIdx.x * EPB;
    const int lane = tid & 63;
    const int w = tid >> 6;
    const int l15 = lane & 15;
    const int l4 = lane >> 4;

    if (tid < EPB) {
        sidx[tid] = src[e0 + tid];
        didx[tid] = dst[e0 + tid];
        tidx[tid] = et[e0 + tid];
    }
    __syncthreads();

    // ---- stage A: gather + f32->bf16 ----
    {
        const int half = tid >> 7;          // 0: src row, 1: dst row
        const int tt = tid & 127;           // covers 256 f32 as float2
        #pragma unroll 4
        for (int e = 0; e < EPB; e++) {
            const int n = half ? didx[e] : sidx[e];
            const float2 v = *(const float2*)(node_emb + (size_t)n * H + 2 * tt);
            unsigned int p = (unsigned int)f2b(v.x) | ((unsigned int)f2b(v.y) << 16);
            *(unsigned int*)&ein[e * LDE + half * 256 + 2 * tt] = p;
        }
        #pragma unroll
        for (int i = tid; i < EPB * 32; i += 256) {   // type: 32 edges x 32 u32
            const int e = i >> 5, j = i & 31;
            const float2 v = *(const float2*)(type_emb + (size_t)tidx[e] * TYPE_DIM + 2 * j);
            unsigned int p = (unsigned int)f2b(v.x) | ((unsigned int)f2b(v.y) << 16);
            *(unsigned int*)&ein[e * LDE + 512 + 2 * j] = p;
        }
    }
    __syncthreads();

    // ---- GEMM: D[32 x 256] = ein[32 x 576] @ W_edge[576 x 256] ----
    f32x4 acc[2][4];
    #pragma unroll
    for (int mt = 0; mt < 2; mt++)
        #pragma unroll
        for (int nt = 0; nt < 4; nt++)
            acc[mt][nt] = (f32x4){0.f, 0.f, 0.f, 0.f};

    const int colbase = w * 64;
    // A frag: row = mt*16 + l15, k = ks*32 + l4*8 + i  (ds_read_b128)
    const unsigned short* A0 = &ein[l15 * LDE + l4 * 8];
    const unsigned short* A1 = &ein[(16 + l15) * LDE + l4 * 8];
    // B frag: col = colbase + nt*16 + l15, k = ks*32 + l4*8 + i  (global dwordx4, L2)
    const unsigned short* B0 = WE + (size_t)(colbase + l15) * KE + l4 * 8;
    const unsigned short* B1 = B0 + 16 * KE;
    const unsigned short* B2 = B0 + 32 * KE;
    const unsigned short* B3 = B0 + 48 * KE;

    for (int ks = 0; ks < KE / 32; ks++) {
        const int o = ks * 32;
        bf16x8 a0 = __builtin_bit_cast(bf16x8, *(const uint4*)(A0 + o));
        bf16x8 a1 = __builtin_bit_cast(bf16x8, *(const uint4*)(A1 + o));
        bf16x8 b0 = __builtin_bit_cast(bf16x8, *(const uint4*)(B0 + o));
        bf16x8 b1 = __builtin_bit_cast(bf16x8, *(const uint4*)(B1 + o));
        bf16x8 b2 = __builtin_bit_cast(bf16x8, *(const uint4*)(B2 + o));
        bf16x8 b3 = __builtin_bit_cast(bf16x8, *(const uint4*)(B3 + o));
        acc[0][0] = __builtin_amdgcn_mfma_f32_16x16x32_bf16(a0, b0, acc[0][0], 0, 0, 0);
        acc[0][1] = __builtin_amdgcn_mfma_f32_16x16x32_bf16(a0, b1, acc[0][1], 0, 0, 0);
        acc[0][2] = __builtin_amdgcn_mfma_f32_16x16x32_bf16(a0, b2, acc[0][2], 0, 0, 0);
        acc[0][3] = __builtin_amdgcn_mfma_f32_16x16x32_bf16(a0, b3, acc[0][3], 0, 0, 0);
        acc[1][0] = __builtin_amdgcn_mfma_f32_16x16x32_bf16(a1, b0, acc[1][0], 0, 0, 0);
        acc[1][1] = __builtin_amdgcn_mfma_f32_16x16x32_bf16(a1, b1, acc[1][1], 0, 0, 0);
        acc[1][2] = __builtin_amdgcn_mfma_f32_16x16x32_bf16(a1, b2, acc[1][2], 0, 0, 0);
        acc[1][3] = __builtin_amdgcn_mfma_f32_16x16x32_bf16(a1, b3, acc[1][3], 0, 0, 0);
    }

    __syncthreads();                       // ein dead; reuse LDS as f32 fout[32][260]
    float* fout = (float*)&ein[0];

    // ---- spill acc (+bias) to LDS. D layout (m89): col=l&15, row=(l>>4)*4+reg ----
    float bias[4];
    #pragma unroll
    for (int nt = 0; nt < 4; nt++) bias[nt] = b_edge[colbase + nt * 16 + l15];
    #pragma unroll
    for (int mt = 0; mt < 2; mt++)
        #pragma unroll
        for (int nt = 0; nt < 4; nt++)
            #pragma unroll
            for (int r = 0; r < 4; r++) {
                int row = mt * 16 + l4 * 4 + r;
                fout[row * LDF + colbase + nt * 16 + l15] = acc[mt][nt][r] + bias[nt];
            }
    __syncthreads();

    // ---- per-row LN + ReLU + scatter; wave w owns rows w*8 .. w*8+7 ----
    const float4 gv = *(const float4*)(ln_g + 4 * lane);
    const float4 bv = *(const float4*)(ln_b + 4 * lane);
    for (int rr = 0; rr < 8; rr++) {
        const int row = w * 8 + rr;
        f32x4 v = *(const f32x4*)&fout[row * LDF + 4 * lane];
        float s1 = v[0] + v[1] + v[2] + v[3];
        float s2 = v[0] * v[0] + v[1] * v[1] + v[2] * v[2] + v[3] * v[3];
        #pragma unroll
        for (int o = 32; o > 0; o >>= 1) {
            s1 += __shfl_down(s1, o, 64);
            s2 += __shfl_down(s2, o, 64);
        }
        const float m = __shfl(s1, 0, 64) * (1.0f / (float)H);
        const float q = __shfl(s2, 0, 64) * (1.0f / (float)H);
        const float is = rsqrtf(fmaxf(q - m * m, 0.0f) + 1e-5f);
        float* dp = agg + (size_t)didx[row] * H + 4 * lane;
        atomicAdd(dp + 0, fmaxf((v[0] - m) * is * gv.x + bv.x, 0.0f));
        atomicAdd(dp + 1, fmaxf((v[1] - m) * is * gv.y + bv.y, 0.0f));
        atomicAdd(dp + 2, fmaxf((v[2] - m) * is * gv.z + bv.z, 0.0f));
        atomicAdd(dp + 3, fmaxf((v[3] - m) * is * gv.w + bv.w, 0.0f));
    }
    if (tid < EPB) {
        int d = didx[tid];
        atomicAdd(&cntw[d >> 2], 1u << ((d & 3) * 8));   // u8-packed count
    }
}

// ---------------- gate fusion + GRU + LN (unchanged math) ------------------
__global__ __launch_bounds__(256) void node_kernel(
    const float* __restrict__ node_emb, const float* __restrict__ h_prev,
    const float* __restrict__ W_gate, const float* __restrict__ b_gate,
    const float* __restrict__ lng_g, const float* __restrict__ lng_b,
    const bf16* __restrict__ WT_ih, const bf16* __restrict__ WT_hh,
    const float* __restrict__ b_ih, const float* __restrict__ b_hh,
    const float* __restrict__ lnr_g, const float* __restrict__ lnr_b,
    const unsigned int* __restrict__ cntw,
    float* __restrict__ out) {   // out doubles as agg (f32) on input
    __shared__ float xn[NPB][H];
    __shared__ float en[NPB][H];
    __shared__ float hp[NPB][H];
    __shared__ float wred[8];
    __shared__ float stats[2];

    const int tid = threadIdx.x;
    const int n0 = blockIdx.x * NPB;
    const int lane = tid & 63, wid = tid >> 6;

    for (int e = 0; e < NPB; e++) {
        size_t n = (size_t)(n0 + e);
        unsigned int cw = cntw[n >> 2];
        float c = (float)((cw >> ((n & 3) * 8)) & 0xFFu);
        float rc = 1.0f / fmaxf(c, 1.0f);
        xn[e][tid] = node_emb[n * H + tid];
        hp[e][tid] = h_prev[n * H + tid];
        en[e][tid] = out[n * H + tid] * rc;
    }
    __syncthreads();

    float accg[NPB];
    const float bg = b_gate[tid];
    #pragma unroll
    for (int e = 0; e < NPB; e++) accg[e] = bg;

    #pragma unroll 4
    for (int k = 0; k < H; k++) {
        float w1 = W_gate[k * H + tid];
        float w2 = W_gate[(k + H) * H + tid];
        #pragma unroll
        for (int e = 0; e < NPB; e++)
            accg[e] += xn[e][k] * w1 + en[e][k] * w2;
    }

    const float gg = lng_g[tid], gb = lng_b[tid];
    for (int e = 0; e < NPB; e++) {
        float v = accg[e];
        float s1 = v, s2 = v * v;
        for (int o = 32; o > 0; o >>= 1) {
            s1 += __shfl_down(s1, o, 64);
            s2 += __shfl_down(s2, o, 64);
        }
        if (lane == 0) { wred[wid] = s1; wred[4 + wid] = s2; }
        __syncthreads();
        if (tid == 0) {
            float t1 = wred[0] + wred[1] + wred[2] + wred[3];
            float t2 = wred[4] + wred[5] + wred[6] + wred[7];
            float m = t1 / (float)H;
            float var = fmaxf(t2 / (float)H - m * m, 0.0f);
            stats[0] = m; stats[1] = rsqrtf(var + 1e-5f);
        }
        __syncthreads();
        float m = stats[0], is = stats[1];
        float u = (v - m) * is * gg + gb;
        float gate = 1.0f / (1.0f + __expf(-u));
        float xnv = xn[e][tid];
        float env = en[e][tid];
        float fused = gate * xnv + (1.0f - gate) * env;
        xn[e][tid] = 0.2f * xnv + 0.8f * fused;   // x
    }
    __syncthreads();

    float gi0[NPB], gi1[NPB], gi2[NPB], gh0[NPB], gh1[NPB], gh2[NPB];
    const float bi0 = b_ih[tid], bi1 = b_ih[H + tid], bi2 = b_ih[2 * H + tid];
    const float bh0 = b_hh[tid], bh1 = b_hh[H + tid], bh2 = b_hh[2 * H + tid];
    #pragma unroll
    for (int e = 0; e < NPB; e++) {
        gi0[e] = bi0; gi1[e] = bi1; gi2[e] = bi2;
        gh0[e] = bh0; gh1[e] = bh1; gh2[e] = bh2;
    }

    #pragma unroll 2
    for (int k = 0; k < H; k++) {
        float wi0 = b2f(WT_ih[k * 768 + tid]);
        float wi1 = b2f(WT_ih[k * 768 + H + tid]);
        float wi2 = b2f(WT_ih[k * 768 + 2 * H + tid]);
        float wh0 = b2f(WT_hh[k * 768 + tid]);
        float wh1 = b2f(WT_hh[k * 768 + H + tid]);
        float wh2 = b2f(WT_hh[k * 768 + 2 * H + tid]);
        #pragma unroll
        for (int e = 0; e < NPB; e++) {
            float xk = xn[e][k], hk = hp[e][k];
            gi0[e] += xk * wi0; gi1[e] += xk * wi1; gi2[e] += xk * wi2;
            gh0[e] += hk * wh0; gh1[e] += hk * wh1; gh2[e] += hk * wh2;
        }
    }

    const float rg = lnr_g[tid], rb = lnr_b[tid];
    for (int e = 0; e < NPB; e++) {
        float r = 1.0f / (1.0f + __expf(-(gi0[e] + gh0[e])));
        float z = 1.0f / (1.0f + __expf(-(gi1[e] + gh1[e])));
        float nn = tanhf(gi2[e] + r * gh2[e]);
        float hpv = hp[e][tid];
        float h = (1.0f - z) * nn + z * hpv;
        float s1 = h, s2 = h * h;
        for (int o = 32; o > 0; o >>= 1) {
            s1 += __shfl_down(s1, o, 64);
            s2 += __shfl_down(s2, o, 64);
        }
        if (lane == 0) { wred[wid] = s1; wred[4 + wid] = s2; }
        __syncthreads();
        if (tid == 0) {
            float t1 = wred[0] + wred[1] + wred[2] + wred[3];
            float t2 = wred[4] + wred[5] + wred[6] + wred[7];
            float m = t1 / (float)H;
            float var = fmaxf(t2 / (float)H - m * m, 0.0f);
            stats[0] = m; stats[1] = rsqrtf(var + 1e-5f);
        }
        __syncthreads();
        float m = stats[0], is = stats[1];
        float ho = (h - m) * is * rg + rb + 0.3f * hpv;
        out[(size_t)(n0 + e) * H + tid] = ho;
    }
}

extern "C" void kernel_launch(void* const* d_in, const int* in_sizes, int n_in,
                              void* d_out, int out_size, void* d_ws, size_t ws_size,
                              hipStream_t stream) {
    const float* node_emb  = (const float*)d_in[0];
    const float* h_prev    = (const float*)d_in[1];
    const float* type_emb  = (const float*)d_in[2];
    const float* W_edge    = (const float*)d_in[3];
    const float* b_edge    = (const float*)d_in[4];
    const float* ln_edge_g = (const float*)d_in[5];
    const float* ln_edge_b = (const float*)d_in[6];
    const float* W_gate    = (const float*)d_in[7];
    const float* b_gate    = (const float*)d_in[8];
    const float* ln_gate_g = (const float*)d_in[9];
    const float* ln_gate_b = (const float*)d_in[10];
    const float* W_ih      = (const float*)d_in[11];
    const float* W_hh      = (const float*)d_in[12];
    const float* b_ih      = (const float*)d_in[13];
    const float* b_hh      = (const float*)d_in[14];
    const float* ln_gru_g  = (const float*)d_in[15];
    const float* ln_gru_b  = (const float*)d_in[16];
    const int*   src       = (const int*)d_in[17];
    const int*   dst       = (const int*)d_in[18];
    const int*   et        = (const int*)d_in[19];
    float* out = (float*)d_out;

    // workspace layout (peak 886,432 B < 1 MiB) — WE and WT time-share:
    //   [0, 100000)        cnt: u8-packed counts, 4/word
    //   [100000, 394912)   WE  bf16 256x576 (edge phase only)
    //   [100000, 886432)   WTih/WThh bf16 256x768 each (node phase; written
    //                      AFTER edge_mfma completes — stream-ordered overwrite)
    char* ws = (char*)d_ws;
    unsigned int* cntw = (unsigned int*)ws;
    unsigned short* WE = (unsigned short*)(ws + 100000);
    bf16* WTih = (bf16*)(ws + 100000);
    bf16* WThh = WTih + (size_t)256 * 768;

    hipMemsetAsync(cntw, 0, 100000, stream);
    hipMemsetAsync(out, 0, (size_t)N_ENTS * H * sizeof(float), stream);

    hipLaunchKernelGGL(transpose_we, dim3(256), dim3(256), 0, stream, W_edge, WE);

    hipLaunchKernelGGL(edge_mfma, dim3(N_EDGES / EPB), dim3(256), 0, stream,
                       node_emb, type_emb, WE, b_edge, ln_edge_g, ln_edge_b,
                       src, dst, et, out, cntw);

    hipLaunchKernelGGL(transpose_kernel, dim3(768), dim3(256), 0, stream,
                       W_ih, W_hh, WTih, WThh);

    hipLaunchKernelGGL(node_kernel, dim3(N_ENTS / NPB), dim3(256), 0, stream,
                       node_emb, h_prev, W_gate, b_gate, ln_gate_g, ln_gate_b,
                       WTih, WThh, b_ih, b_hh, ln_gru_g, ln_gru_b,
                       cntw, out);
}

// Round 2
// 1754.223 us; speedup vs baseline: 1.5719x; 1.5719x over previous
//
#include <hip/hip_runtime.h>
#include <hip/hip_bf16.h>

#define H 256
#define TYPE_DIM 64
#define EIN (2*H + TYPE_DIM)   // 576
#define N_ENTS 100000
#define N_EDGES 200000
#define EPB 32                  // edges per block (MFMA M=32)
#define NPB 32                  // nodes per block (MFMA M=32)
#define KE 576                  // K of edge GEMM
#define LDE 584                 // padded LDS row (bf16): stride 1168B -> 2-way alias (free)
#define LDF 260                 // padded f32 row for epilogue buffers
#define LDA 520                 // node gate-A row (bf16): 512 + 8
#define LDH 264                 // hp/u rows (bf16): 256 + 8 (16B-aligned stride)

typedef __hip_bfloat16 bf16;
typedef short bf16x8 __attribute__((ext_vector_type(8)));  // MFMA a/b frag
typedef float f32x4 __attribute__((ext_vector_type(4)));   // MFMA acc frag

__device__ __forceinline__ float b2f(bf16 x) { return __bfloat162float(x); }

// f32 -> bf16 bits, RNE (matches __float2bfloat16)
__device__ __forceinline__ unsigned short f2b(float f) {
    union { float f; unsigned int u; } v; v.f = f;
    unsigned int u = v.u;
    return (unsigned short)((u + 0x7FFFu + ((u >> 16) & 1u)) >> 16);
}
__device__ __forceinline__ unsigned int pack2(float a, float b) {
    return (unsigned int)f2b(a) | ((unsigned int)f2b(b) << 16);
}
__device__ __forceinline__ float u2f(unsigned short u) {   // bf16 bits -> f32
    union { unsigned int i; float f; } t; t.i = ((unsigned int)u) << 16; return t.f;
}
__device__ __forceinline__ float sigm(float x) { return 1.0f / (1.0f + __expf(-x)); }

// 8 contiguous f32 -> bf16x8 (compiler emits v_cvt_pk_bf16_f32 pairs)
__device__ __forceinline__ bf16x8 cvt8(const float* p) {
    f32x4 a = *(const f32x4*)p;
    f32x4 b = *(const f32x4*)(p + 4);
    union { bf16 h[8]; bf16x8 v; } u;
    u.h[0] = __float2bfloat16(a[0]); u.h[1] = __float2bfloat16(a[1]);
    u.h[2] = __float2bfloat16(a[2]); u.h[3] = __float2bfloat16(a[3]);
    u.h[4] = __float2bfloat16(b[0]); u.h[5] = __float2bfloat16(b[1]);
    u.h[6] = __float2bfloat16(b[2]); u.h[7] = __float2bfloat16(b[3]);
    return u.v;
}

// ---------------- W_edge -> col-major bf16 (WE[c][k], row len 576) ---------
__global__ void transpose_we(const float* __restrict__ W,
                             unsigned short* __restrict__ WE) {
    int c = blockIdx.x;
    for (int j = threadIdx.x; j < KE; j += 256)
        WE[(size_t)c * KE + j] = f2b(W[(size_t)j * H + c]);
}

// ---------------- W_gate -> col-major bf16 (WG[c][k], row len 512) ---------
__global__ void transpose_wg(const float* __restrict__ W,
                             unsigned short* __restrict__ WG) {
    int c = blockIdx.x;                    // 0..255
    for (int k = threadIdx.x; k < 2 * H; k += 256)
        WG[(size_t)c * (2 * H) + k] = f2b(W[(size_t)k * H + c]);
}

// ---------------- edge MLP via MFMA + scatter-add (unchanged, verified) ----
__global__ __launch_bounds__(256) void edge_mfma(
    const float* __restrict__ node_emb, const float* __restrict__ type_emb,
    const unsigned short* __restrict__ WE,
    const float* __restrict__ b_edge,
    const float* __restrict__ ln_g, const float* __restrict__ ln_b,
    const int* __restrict__ src, const int* __restrict__ dst,
    const int* __restrict__ et,
    float* __restrict__ agg,
    unsigned int* __restrict__ cntw) {
    __shared__ __align__(16) unsigned short ein[EPB * LDE];
    __shared__ int sidx[EPB], didx[EPB], tidx[EPB];

    const int tid = threadIdx.x;
    const int e0 = blockIdx.x * EPB;
    const int lane = tid & 63;
    const int w = tid >> 6;
    const int l15 = lane & 15;
    const int l4 = lane >> 4;

    if (tid < EPB) {
        sidx[tid] = src[e0 + tid];
        didx[tid] = dst[e0 + tid];
        tidx[tid] = et[e0 + tid];
    }
    __syncthreads();

    {
        const int half = tid >> 7;
        const int tt = tid & 127;
        #pragma unroll 4
        for (int e = 0; e < EPB; e++) {
            const int n = half ? didx[e] : sidx[e];
            const float2 v = *(const float2*)(node_emb + (size_t)n * H + 2 * tt);
            *(unsigned int*)&ein[e * LDE + half * 256 + 2 * tt] = pack2(v.x, v.y);
        }
        #pragma unroll
        for (int i = tid; i < EPB * 32; i += 256) {
            const int e = i >> 5, j = i & 31;
            const float2 v = *(const float2*)(type_emb + (size_t)tidx[e] * TYPE_DIM + 2 * j);
            *(unsigned int*)&ein[e * LDE + 512 + 2 * j] = pack2(v.x, v.y);
        }
    }
    __syncthreads();

    f32x4 acc[2][4];
    #pragma unroll
    for (int mt = 0; mt < 2; mt++)
        #pragma unroll
        for (int nt = 0; nt < 4; nt++)
            acc[mt][nt] = (f32x4){0.f, 0.f, 0.f, 0.f};

    const int colbase = w * 64;
    const unsigned short* A0 = &ein[l15 * LDE + l4 * 8];
    const unsigned short* A1 = &ein[(16 + l15) * LDE + l4 * 8];
    const unsigned short* B0 = WE + (size_t)(colbase + l15) * KE + l4 * 8;
    const unsigned short* B1 = B0 + 16 * KE;
    const unsigned short* B2 = B0 + 32 * KE;
    const unsigned short* B3 = B0 + 48 * KE;

    for (int ks = 0; ks < KE / 32; ks++) {
        const int o = ks * 32;
        bf16x8 a0 = __builtin_bit_cast(bf16x8, *(const uint4*)(A0 + o));
        bf16x8 a1 = __builtin_bit_cast(bf16x8, *(const uint4*)(A1 + o));
        bf16x8 b0 = __builtin_bit_cast(bf16x8, *(const uint4*)(B0 + o));
        bf16x8 b1 = __builtin_bit_cast(bf16x8, *(const uint4*)(B1 + o));
        bf16x8 b2 = __builtin_bit_cast(bf16x8, *(const uint4*)(B2 + o));
        bf16x8 b3 = __builtin_bit_cast(bf16x8, *(const uint4*)(B3 + o));
        acc[0][0] = __builtin_amdgcn_mfma_f32_16x16x32_bf16(a0, b0, acc[0][0], 0, 0, 0);
        acc[0][1] = __builtin_amdgcn_mfma_f32_16x16x32_bf16(a0, b1, acc[0][1], 0, 0, 0);
        acc[0][2] = __builtin_amdgcn_mfma_f32_16x16x32_bf16(a0, b2, acc[0][2], 0, 0, 0);
        acc[0][3] = __builtin_amdgcn_mfma_f32_16x16x32_bf16(a0, b3, acc[0][3], 0, 0, 0);
        acc[1][0] = __builtin_amdgcn_mfma_f32_16x16x32_bf16(a1, b0, acc[1][0], 0, 0, 0);
        acc[1][1] = __builtin_amdgcn_mfma_f32_16x16x32_bf16(a1, b1, acc[1][1], 0, 0, 0);
        acc[1][2] = __builtin_amdgcn_mfma_f32_16x16x32_bf16(a1, b2, acc[1][2], 0, 0, 0);
        acc[1][3] = __builtin_amdgcn_mfma_f32_16x16x32_bf16(a1, b3, acc[1][3], 0, 0, 0);
    }

    __syncthreads();
    float* fout = (float*)&ein[0];

    float bias[4];
    #pragma unroll
    for (int nt = 0; nt < 4; nt++) bias[nt] = b_edge[colbase + nt * 16 + l15];
    #pragma unroll
    for (int mt = 0; mt < 2; mt++)
        #pragma unroll
        for (int nt = 0; nt < 4; nt++)
            #pragma unroll
            for (int r = 0; r < 4; r++) {
                int row = mt * 16 + l4 * 4 + r;
                fout[row * LDF + colbase + nt * 16 + l15] = acc[mt][nt][r] + bias[nt];
            }
    __syncthreads();

    const float4 gv = *(const float4*)(ln_g + 4 * lane);
    const float4 bv = *(const float4*)(ln_b + 4 * lane);
    for (int rr = 0; rr < 8; rr++) {
        const int row = w * 8 + rr;
        f32x4 v = *(const f32x4*)&fout[row * LDF + 4 * lane];
        float s1 = v[0] + v[1] + v[2] + v[3];
        float s2 = v[0] * v[0] + v[1] * v[1] + v[2] * v[2] + v[3] * v[3];
        #pragma unroll
        for (int o = 32; o > 0; o >>= 1) {
            s1 += __shfl_down(s1, o, 64);
            s2 += __shfl_down(s2, o, 64);
        }
        const float m = __shfl(s1, 0, 64) * (1.0f / (float)H);
        const float q = __shfl(s2, 0, 64) * (1.0f / (float)H);
        const float is = rsqrtf(fmaxf(q - m * m, 0.0f) + 1e-5f);
        float* dp = agg + (size_t)didx[row] * H + 4 * lane;
        atomicAdd(dp + 0, fmaxf((v[0] - m) * is * gv.x + bv.x, 0.0f));
        atomicAdd(dp + 1, fmaxf((v[1] - m) * is * gv.y + bv.y, 0.0f));
        atomicAdd(dp + 2, fmaxf((v[2] - m) * is * gv.z + bv.z, 0.0f));
        atomicAdd(dp + 3, fmaxf((v[3] - m) * is * gv.w + bv.w, 0.0f));
    }
    if (tid < EPB) {
        int d = didx[tid];
        atomicAdd(&cntw[d >> 2], 1u << ((d & 3) * 8));
    }
}

// ---------------- node phase: gate + GRU, all GEMMs on MFMA ----------------
// 512 thr (8 waves), 32 nodes. Wave w owns cols [w*32, w*32+32) of each segment.
__global__ __launch_bounds__(512) void node_mfma(
    const float* __restrict__ node_emb, const float* __restrict__ h_prev,
    const unsigned short* __restrict__ WG, const float* __restrict__ b_gate,
    const float* __restrict__ lng_g, const float* __restrict__ lng_b,
    const float* __restrict__ W_ih, const float* __restrict__ W_hh,
    const float* __restrict__ b_ih, const float* __restrict__ b_hh,
    const float* __restrict__ lnr_g, const float* __restrict__ lnr_b,
    const unsigned int* __restrict__ cntw,
    float* __restrict__ out) {   // out holds agg (f32) on input
    // Aga: [32][520] bf16 = xn|en; cols<256 overwritten with x; finally f32 h[32][260]
    __shared__ __align__(16) unsigned short Aga[NPB * LDA];   // 33280 B
    __shared__ __align__(16) unsigned short hpb[NPB * LDH];   // 16896 B (h_prev bf16)
    __shared__ __align__(16) unsigned short ubf[NPB * LDH];   // 16896 B (gate pre-LN, bf16)
    __shared__ float rc[NPB];

    const int tid = threadIdx.x;
    const int n0 = blockIdx.x * NPB;
    const int lane = tid & 63;
    const int w = tid >> 6;          // 0..7
    const int l15 = lane & 15, l4 = lane >> 4;

    if (tid < NPB) {
        int n = n0 + tid;
        unsigned int cw = cntw[n >> 2];
        float c = (float)((cw >> ((n & 3) * 8)) & 0xFFu);
        rc[tid] = 1.0f / fmaxf(c, 1.0f);
    }
    __syncthreads();

    // ---- stage xn|en (Aga) and hp (hpb) as bf16 ----
    #pragma unroll
    for (int i = tid; i < NPB * 128; i += 512) {
        int row = i >> 7, c2 = (i & 127) * 2;
        size_t g = (size_t)(n0 + row) * H + c2;
        float2 xv = *(const float2*)(node_emb + g);
        float2 hv = *(const float2*)(h_prev + g);
        float2 ev = *(const float2*)(out + g);
        float r = rc[row];
        *(unsigned int*)&Aga[row * LDA + c2]       = pack2(xv.x, xv.y);
        *(unsigned int*)&Aga[row * LDA + 256 + c2] = pack2(ev.x * r, ev.y * r);
        *(unsigned int*)&hpb[row * LDH + c2]       = pack2(hv.x, hv.y);
    }
    __syncthreads();

    // ---- gate GEMM: u[32x256] = [xn|en] @ W_gate, K=512 ----
    {
        f32x4 acc[2][2];   // [mt][nt]
        #pragma unroll
        for (int mt = 0; mt < 2; mt++)
            #pragma unroll
            for (int nt = 0; nt < 2; nt++) acc[mt][nt] = (f32x4){0.f, 0.f, 0.f, 0.f};
        const unsigned short* A0 = &Aga[l15 * LDA + l4 * 8];
        const unsigned short* A1 = &Aga[(16 + l15) * LDA + l4 * 8];
        const unsigned short* B0 = WG + (size_t)(w * 32 + l15) * (2 * H) + l4 * 8;
        const unsigned short* B1 = B0 + 16 * (2 * H);
        #pragma unroll
        for (int ks = 0; ks < 16; ks++) {
            const int o = ks * 32;
            bf16x8 a0 = __builtin_bit_cast(bf16x8, *(const uint4*)(A0 + o));
            bf16x8 a1 = __builtin_bit_cast(bf16x8, *(const uint4*)(A1 + o));
            bf16x8 b0 = __builtin_bit_cast(bf16x8, *(const uint4*)(B0 + o));
            bf16x8 b1 = __builtin_bit_cast(bf16x8, *(const uint4*)(B1 + o));
            acc[0][0] = __builtin_amdgcn_mfma_f32_16x16x32_bf16(a0, b0, acc[0][0], 0, 0, 0);
            acc[0][1] = __builtin_amdgcn_mfma_f32_16x16x32_bf16(a0, b1, acc[0][1], 0, 0, 0);
            acc[1][0] = __builtin_amdgcn_mfma_f32_16x16x32_bf16(a1, b0, acc[1][0], 0, 0, 0);
            acc[1][1] = __builtin_amdgcn_mfma_f32_16x16x32_bf16(a1, b1, acc[1][1], 0, 0, 0);
        }
        const float bg0 = b_gate[w * 32 + l15];
        const float bg1 = b_gate[w * 32 + 16 + l15];
        #pragma unroll
        for (int mt = 0; mt < 2; mt++)
            #pragma unroll
            for (int r = 0; r < 4; r++) {
                int row = mt * 16 + l4 * 4 + r;
                ubf[row * LDH + w * 32 + l15]      = f2b(acc[mt][0][r] + bg0);
                ubf[row * LDH + w * 32 + 16 + l15] = f2b(acc[mt][1][r] + bg1);
            }
    }
    __syncthreads();

    // ---- gate epilogue: LN(u) -> sigmoid -> fused -> x (bf16, in-place) ----
    {
        const float4 g4 = *(const float4*)(lng_g + 4 * lane);
        const float4 b4 = *(const float4*)(lng_b + 4 * lane);
        for (int rr = 0; rr < 4; rr++) {
            const int row = w * 4 + rr;
            short4 us = *(const short4*)&ubf[row * LDH + 4 * lane];
            float u0 = u2f((unsigned short)us.x), u1 = u2f((unsigned short)us.y);
            float u2 = u2f((unsigned short)us.z), u3 = u2f((unsigned short)us.w);
            float s1 = u0 + u1 + u2 + u3;
            float s2 = u0 * u0 + u1 * u1 + u2 * u2 + u3 * u3;
            #pragma unroll
            for (int o = 32; o > 0; o >>= 1) {
                s1 += __shfl_down(s1, o, 64);
                s2 += __shfl_down(s2, o, 64);
            }
            const float m = __shfl(s1, 0, 64) * (1.0f / (float)H);
            const float q = __shfl(s2, 0, 64) * (1.0f / (float)H);
            const float is = rsqrtf(fmaxf(q - m * m, 0.0f) + 1e-5f);
            short4 xr = *(const short4*)&Aga[row * LDA + 4 * lane];
            short4 er = *(const short4*)&Aga[row * LDA + 256 + 4 * lane];
            float xv[4] = {u2f((unsigned short)xr.x), u2f((unsigned short)xr.y),
                           u2f((unsigned short)xr.z), u2f((unsigned short)xr.w)};
            float ev[4] = {u2f((unsigned short)er.x), u2f((unsigned short)er.y),
                           u2f((unsigned short)er.z), u2f((unsigned short)er.w)};
            float uu[4] = {u0, u1, u2, u3};
            float gl[4] = {g4.x, g4.y, g4.z, g4.w};
            float bl[4] = {b4.x, b4.y, b4.z, b4.w};
            unsigned short xs[4];
            #pragma unroll
            for (int j = 0; j < 4; j++) {
                float gate = sigm((uu[j] - m) * is * gl[j] + bl[j]);
                float fused = gate * xv[j] + (1.0f - gate) * ev[j];
                xs[j] = f2b(0.2f * xv[j] + 0.8f * fused);
            }
            unsigned int p0 = (unsigned int)xs[0] | ((unsigned int)xs[1] << 16);
            unsigned int p1 = (unsigned int)xs[2] | ((unsigned int)xs[3] << 16);
            *(unsigned int*)&Aga[row * LDA + 4 * lane]     = p0;
            *(unsigned int*)&Aga[row * LDA + 4 * lane + 2] = p1;
        }
    }
    __syncthreads();

    // ---- GRU GEMMs: gi = x @ W_ih^T, gh = hp @ W_hh^T (B loaded f32-direct) ----
    float hreg[2][2][4];   // [pass][mt][r]
    #pragma unroll
    for (int p = 0; p < 2; p++) {
        f32x4 aI[3][2], aH[3][2];   // [seg][mt]
        #pragma unroll
        for (int s = 0; s < 3; s++)
            #pragma unroll
            for (int mt = 0; mt < 2; mt++) {
                aI[s][mt] = (f32x4){0.f, 0.f, 0.f, 0.f};
                aH[s][mt] = (f32x4){0.f, 0.f, 0.f, 0.f};
            }
        const int cl = w * 32 + p * 16 + l15;          // output col in [0,256)
        const float* pI0 = W_ih + (size_t)(cl) * H + l4 * 8;
        const float* pI1 = W_ih + (size_t)(H + cl) * H + l4 * 8;
        const float* pI2 = W_ih + (size_t)(2 * H + cl) * H + l4 * 8;
        const float* pH0 = W_hh + (size_t)(cl) * H + l4 * 8;
        const float* pH1 = W_hh + (size_t)(H + cl) * H + l4 * 8;
        const float* pH2 = W_hh + (size_t)(2 * H + cl) * H + l4 * 8;
        const unsigned short* X0 = &Aga[l15 * LDA + l4 * 8];
        const unsigned short* X1 = &Aga[(16 + l15) * LDA + l4 * 8];
        const unsigned short* P0 = &hpb[l15 * LDH + l4 * 8];
        const unsigned short* P1 = &hpb[(16 + l15) * LDH + l4 * 8];
        #pragma unroll
        for (int ks = 0; ks < 8; ks++) {
            const int o = ks * 32;
            bf16x8 ax0 = __builtin_bit_cast(bf16x8, *(const uint4*)(X0 + o));
            bf16x8 ax1 = __builtin_bit_cast(bf16x8, *(const uint4*)(X1 + o));
            bf16x8 ah0 = __builtin_bit_cast(bf16x8, *(const uint4*)(P0 + o));
            bf16x8 ah1 = __builtin_bit_cast(bf16x8, *(const uint4*)(P1 + o));
            bf16x8 bI0 = cvt8(pI0 + o);
            bf16x8 bI1 = cvt8(pI1 + o);
            bf16x8 bI2 = cvt8(pI2 + o);
            bf16x8 bH0 = cvt8(pH0 + o);
            bf16x8 bH1 = cvt8(pH1 + o);
            bf16x8 bH2 = cvt8(pH2 + o);
            aI[0][0] = __builtin_amdgcn_mfma_f32_16x16x32_bf16(ax0, bI0, aI[0][0], 0, 0, 0);
            aI[0][1] = __builtin_amdgcn_mfma_f32_16x16x32_bf16(ax1, bI0, aI[0][1], 0, 0, 0);
            aI[1][0] = __builtin_amdgcn_mfma_f32_16x16x32_bf16(ax0, bI1, aI[1][0], 0, 0, 0);
            aI[1][1] = __builtin_amdgcn_mfma_f32_16x16x32_bf16(ax1, bI1, aI[1][1], 0, 0, 0);
            aI[2][0] = __builtin_amdgcn_mfma_f32_16x16x32_bf16(ax0, bI2, aI[2][0], 0, 0, 0);
            aI[2][1] = __builtin_amdgcn_mfma_f32_16x16x32_bf16(ax1, bI2, aI[2][1], 0, 0, 0);
            aH[0][0] = __builtin_amdgcn_mfma_f32_16x16x32_bf16(ah0, bH0, aH[0][0], 0, 0, 0);
            aH[0][1] = __builtin_amdgcn_mfma_f32_16x16x32_bf16(ah1, bH0, aH[0][1], 0, 0, 0);
            aH[1][0] = __builtin_amdgcn_mfma_f32_16x16x32_bf16(ah0, bH1, aH[1][0], 0, 0, 0);
            aH[1][1] = __builtin_amdgcn_mfma_f32_16x16x32_bf16(ah1, bH1, aH[1][1], 0, 0, 0);
            aH[2][0] = __builtin_amdgcn_mfma_f32_16x16x32_bf16(ah0, bH2, aH[2][0], 0, 0, 0);
            aH[2][1] = __builtin_amdgcn_mfma_f32_16x16x32_bf16(ah1, bH2, aH[2][1], 0, 0, 0);
        }
        // elementwise GRU for this pass's 16 cols (keep h in regs)
        const float bi0 = b_ih[cl], bi1 = b_ih[H + cl], bi2 = b_ih[2 * H + cl];
        const float bh0 = b_hh[cl], bh1 = b_hh[H + cl], bh2 = b_hh[2 * H + cl];
        #pragma unroll
        for (int mt = 0; mt < 2; mt++)
            #pragma unroll
            for (int r = 0; r < 4; r++) {
                const int row = mt * 16 + l4 * 4 + r;
                float rg = sigm(aI[0][mt][r] + bi0 + aH[0][mt][r] + bh0);
                float zg = sigm(aI[1][mt][r] + bi1 + aH[1][mt][r] + bh1);
                float nn = tanhf(aI[2][mt][r] + bi2 + rg * (aH[2][mt][r] + bh2));
                float hpv = h_prev[(size_t)(n0 + row) * H + cl];
                hreg[p][mt][r] = (1.0f - zg) * nn + zg * hpv;
            }
    }
    __syncthreads();   // all waves done reading Aga/hpb -> reuse Aga as f32 h

    float* hb = (float*)&Aga[0];   // [32][260] f32
    #pragma unroll
    for (int p = 0; p < 2; p++) {
        const int cl = w * 32 + p * 16 + l15;
        #pragma unroll
        for (int mt = 0; mt < 2; mt++)
            #pragma unroll
            for (int r = 0; r < 4; r++)
                hb[(mt * 16 + l4 * 4 + r) * LDF + cl] = hreg[p][mt][r];
    }
    __syncthreads();

    // ---- final LN + 0.3*h_prev residual ----
    {
        const float4 g4 = *(const float4*)(lnr_g + 4 * lane);
        const float4 b4 = *(const float4*)(lnr_b + 4 * lane);
        for (int rr = 0; rr < 4; rr++) {
            const int row = w * 4 + rr;
            f32x4 hv = *(const f32x4*)&hb[row * LDF + 4 * lane];
            float s1 = hv[0] + hv[1] + hv[2] + hv[3];
            float s2 = hv[0] * hv[0] + hv[1] * hv[1] + hv[2] * hv[2] + hv[3] * hv[3];
            #pragma unroll
            for (int o = 32; o > 0; o >>= 1) {
                s1 += __shfl_down(s1, o, 64);
                s2 += __shfl_down(s2, o, 64);
            }
            const float m = __shfl(s1, 0, 64) * (1.0f / (float)H);
            const float q = __shfl(s2, 0, 64) * (1.0f / (float)H);
            const float is = rsqrtf(fmaxf(q - m * m, 0.0f) + 1e-5f);
            const float4 hp4 = *(const float4*)(h_prev + (size_t)(n0 + row) * H + 4 * lane);
            float4 o4;
            o4.x = (hv[0] - m) * is * g4.x + b4.x + 0.3f * hp4.x;
            o4.y = (hv[1] - m) * is * g4.y + b4.y + 0.3f * hp4.y;
            o4.z = (hv[2] - m) * is * g4.z + b4.z + 0.3f * hp4.z;
            o4.w = (hv[3] - m) * is * g4.w + b4.w + 0.3f * hp4.w;
            *(float4*)(out + (size_t)(n0 + row) * H + 4 * lane) = o4;
        }
    }
}

extern "C" void kernel_launch(void* const* d_in, const int* in_sizes, int n_in,
                              void* d_out, int out_size, void* d_ws, size_t ws_size,
                              hipStream_t stream) {
    (void)in_sizes; (void)n_in; (void)out_size; (void)ws_size;
    const float* node_emb  = (const float*)d_in[0];
    const float* h_prev    = (const float*)d_in[1];
    const float* type_emb  = (const float*)d_in[2];
    const float* W_edge    = (const float*)d_in[3];
    const float* b_edge    = (const float*)d_in[4];
    const float* ln_edge_g = (const float*)d_in[5];
    const float* ln_edge_b = (const float*)d_in[6];
    const float* W_gate    = (const float*)d_in[7];
    const float* b_gate    = (const float*)d_in[8];
    const float* ln_gate_g = (const float*)d_in[9];
    const float* ln_gate_b = (const float*)d_in[10];
    const float* W_ih      = (const float*)d_in[11];
    const float* W_hh      = (const float*)d_in[12];
    const float* b_ih      = (const float*)d_in[13];
    const float* b_hh      = (const float*)d_in[14];
    const float* ln_gru_g  = (const float*)d_in[15];
    const float* ln_gru_b  = (const float*)d_in[16];
    const int*   src       = (const int*)d_in[17];
    const int*   dst       = (const int*)d_in[18];
    const int*   et        = (const int*)d_in[19];
    float* out = (float*)d_out;

    // workspace (peak 394,912 B):
    //   [0, 100000)        cnt: u8-packed counts, 4/word
    //   [100000, 394912)   WE bf16 256x576 (edge phase)
    //   [100000, 362144)   WG bf16 256x512 (node phase; overwrites WE after edge)
    char* ws = (char*)d_ws;
    unsigned int* cntw = (unsigned int*)ws;
    unsigned short* WE = (unsigned short*)(ws + 100000);
    unsigned short* WG = (unsigned short*)(ws + 100000);

    hipMemsetAsync(cntw, 0, 100000, stream);
    hipMemsetAsync(out, 0, (size_t)N_ENTS * H * sizeof(float), stream);

    hipLaunchKernelGGL(transpose_we, dim3(256), dim3(256), 0, stream, W_edge, WE);

    hipLaunchKernelGGL(edge_mfma, dim3(N_EDGES / EPB), dim3(256), 0, stream,
                       node_emb, type_emb, WE, b_edge, ln_edge_g, ln_edge_b,
                       src, dst, et, out, cntw);

    hipLaunchKernelGGL(transpose_wg, dim3(256), dim3(256), 0, stream, W_gate, WG);

    hipLaunchKernelGGL(node_mfma, dim3(N_ENTS / NPB), dim3(512), 0, stream,
                       node_emb, h_prev, WG, b_gate, ln_gate_g, ln_gate_b,
                       W_ih, W_hh, b_ih, b_hh, ln_gru_g, ln_gru_b,
                       cntw, out);
}

// Round 3
// 1441.207 us; speedup vs baseline: 1.9134x; 1.2172x over previous
//
#include <hip/hip_runtime.h>
#include <hip/hip_bf16.h>

#define H 256
#define TYPE_DIM 64
#define EIN (2*H + TYPE_DIM)   // 576
#define N_ENTS 100000
#define N_EDGES 200000
#define EPB 32                  // edges per block (MFMA M=32)
#define NPB 64                  // nodes per block (MFMA M=64, 4 m-frags/wave)
#define KE 576                  // K of edge GEMM
#define LDE 584                 // edge LDS row (bf16)
#define LDF 260                 // padded f32 row (edge epilogue)
#define LDA 520                 // node gate-A row (bf16): 512+8 (2-way bank alias = free)
#define LDH 264                 // u/hp rows (bf16): 256+8
#define LDF2 260                // f32 overlay stride (node final h)

typedef __hip_bfloat16 bf16;
typedef short bf16x8 __attribute__((ext_vector_type(8)));
typedef float f32x4 __attribute__((ext_vector_type(4)));

__device__ __forceinline__ unsigned short f2b(float f) {
    union { float f; unsigned int u; } v; v.f = f;
    unsigned int u = v.u;
    return (unsigned short)((u + 0x7FFFu + ((u >> 16) & 1u)) >> 16);
}
__device__ __forceinline__ unsigned int pack2(float a, float b) {
    return (unsigned int)f2b(a) | ((unsigned int)f2b(b) << 16);
}
__device__ __forceinline__ float u2f(unsigned short u) {
    union { unsigned int i; float f; } t; t.i = ((unsigned int)u) << 16; return t.f;
}
__device__ __forceinline__ float sigm(float x) { return 1.0f / (1.0f + __expf(-x)); }

__device__ __forceinline__ bf16x8 cvt8(const float* p) {
    f32x4 a = *(const f32x4*)p;
    f32x4 b = *(const f32x4*)(p + 4);
    union { bf16 h[8]; bf16x8 v; } u;
    u.h[0] = __float2bfloat16(a[0]); u.h[1] = __float2bfloat16(a[1]);
    u.h[2] = __float2bfloat16(a[2]); u.h[3] = __float2bfloat16(a[3]);
    u.h[4] = __float2bfloat16(b[0]); u.h[5] = __float2bfloat16(b[1]);
    u.h[6] = __float2bfloat16(b[2]); u.h[7] = __float2bfloat16(b[3]);
    return u.v;
}

// ---------------- W_edge -> col-major bf16 (WE[c][k], row len 576) ---------
__global__ void transpose_we(const float* __restrict__ W,
                             unsigned short* __restrict__ WE) {
    int c = blockIdx.x;
    for (int j = threadIdx.x; j < KE; j += 256)
        WE[(size_t)c * KE + j] = f2b(W[(size_t)j * H + c]);
}

// ---------------- W_gate -> col-major bf16 (WG[c][k], row len 512) ---------
__global__ void transpose_wg(const float* __restrict__ W,
                             unsigned short* __restrict__ WG) {
    int c = blockIdx.x;
    for (int k = threadIdx.x; k < 2 * H; k += 256)
        WG[(size_t)c * (2 * H) + k] = f2b(W[(size_t)k * H + c]);
}

// ---------------- W_ih/W_hh f32 -> bf16 straight cast (layout kept) --------
__global__ void cast_gru(const float* __restrict__ Wih, const float* __restrict__ Whh,
                         unsigned short* __restrict__ WTih,
                         unsigned short* __restrict__ WThh, int do_hh) {
    int j = blockIdx.x;      // 0..767
    int k = threadIdx.x;     // 0..255
    WTih[(size_t)j * H + k] = f2b(Wih[(size_t)j * H + k]);
    if (do_hh) WThh[(size_t)j * H + k] = f2b(Whh[(size_t)j * H + k]);
}

// ---------------- edge MLP via MFMA + scatter-add (unchanged, verified) ----
__global__ __launch_bounds__(256) void edge_mfma(
    const float* __restrict__ node_emb, const float* __restrict__ type_emb,
    const unsigned short* __restrict__ WE,
    const float* __restrict__ b_edge,
    const float* __restrict__ ln_g, const float* __restrict__ ln_b,
    const int* __restrict__ src, const int* __restrict__ dst,
    const int* __restrict__ et,
    float* __restrict__ agg,
    unsigned int* __restrict__ cntw) {
    __shared__ __align__(16) unsigned short ein[EPB * LDE];
    __shared__ int sidx[EPB], didx[EPB], tidx[EPB];

    const int tid = threadIdx.x;
    const int e0 = blockIdx.x * EPB;
    const int lane = tid & 63;
    const int w = tid >> 6;
    const int l15 = lane & 15;
    const int l4 = lane >> 4;

    if (tid < EPB) {
        sidx[tid] = src[e0 + tid];
        didx[tid] = dst[e0 + tid];
        tidx[tid] = et[e0 + tid];
    }
    __syncthreads();

    {
        const int half = tid >> 7;
        const int tt = tid & 127;
        #pragma unroll 4
        for (int e = 0; e < EPB; e++) {
            const int n = half ? didx[e] : sidx[e];
            const float2 v = *(const float2*)(node_emb + (size_t)n * H + 2 * tt);
            *(unsigned int*)&ein[e * LDE + half * 256 + 2 * tt] = pack2(v.x, v.y);
        }
        #pragma unroll
        for (int i = tid; i < EPB * 32; i += 256) {
            const int e = i >> 5, j = i & 31;
            const float2 v = *(const float2*)(type_emb + (size_t)tidx[e] * TYPE_DIM + 2 * j);
            *(unsigned int*)&ein[e * LDE + 512 + 2 * j] = pack2(v.x, v.y);
        }
    }
    __syncthreads();

    f32x4 acc[2][4];
    #pragma unroll
    for (int mt = 0; mt < 2; mt++)
        #pragma unroll
        for (int nt = 0; nt < 4; nt++)
            acc[mt][nt] = (f32x4){0.f, 0.f, 0.f, 0.f};

    const int colbase = w * 64;
    const unsigned short* A0 = &ein[l15 * LDE + l4 * 8];
    const unsigned short* A1 = &ein[(16 + l15) * LDE + l4 * 8];
    const unsigned short* B0 = WE + (size_t)(colbase + l15) * KE + l4 * 8;
    const unsigned short* B1 = B0 + 16 * KE;
    const unsigned short* B2 = B0 + 32 * KE;
    const unsigned short* B3 = B0 + 48 * KE;

    for (int ks = 0; ks < KE / 32; ks++) {
        const int o = ks * 32;
        bf16x8 a0 = __builtin_bit_cast(bf16x8, *(const uint4*)(A0 + o));
        bf16x8 a1 = __builtin_bit_cast(bf16x8, *(const uint4*)(A1 + o));
        bf16x8 b0 = __builtin_bit_cast(bf16x8, *(const uint4*)(B0 + o));
        bf16x8 b1 = __builtin_bit_cast(bf16x8, *(const uint4*)(B1 + o));
        bf16x8 b2 = __builtin_bit_cast(bf16x8, *(const uint4*)(B2 + o));
        bf16x8 b3 = __builtin_bit_cast(bf16x8, *(const uint4*)(B3 + o));
        acc[0][0] = __builtin_amdgcn_mfma_f32_16x16x32_bf16(a0, b0, acc[0][0], 0, 0, 0);
        acc[0][1] = __builtin_amdgcn_mfma_f32_16x16x32_bf16(a0, b1, acc[0][1], 0, 0, 0);
        acc[0][2] = __builtin_amdgcn_mfma_f32_16x16x32_bf16(a0, b2, acc[0][2], 0, 0, 0);
        acc[0][3] = __builtin_amdgcn_mfma_f32_16x16x32_bf16(a0, b3, acc[0][3], 0, 0, 0);
        acc[1][0] = __builtin_amdgcn_mfma_f32_16x16x32_bf16(a1, b0, acc[1][0], 0, 0, 0);
        acc[1][1] = __builtin_amdgcn_mfma_f32_16x16x32_bf16(a1, b1, acc[1][1], 0, 0, 0);
        acc[1][2] = __builtin_amdgcn_mfma_f32_16x16x32_bf16(a1, b2, acc[1][2], 0, 0, 0);
        acc[1][3] = __builtin_amdgcn_mfma_f32_16x16x32_bf16(a1, b3, acc[1][3], 0, 0, 0);
    }

    __syncthreads();
    float* fout = (float*)&ein[0];

    float bias[4];
    #pragma unroll
    for (int nt = 0; nt < 4; nt++) bias[nt] = b_edge[colbase + nt * 16 + l15];
    #pragma unroll
    for (int mt = 0; mt < 2; mt++)
        #pragma unroll
        for (int nt = 0; nt < 4; nt++)
            #pragma unroll
            for (int r = 0; r < 4; r++) {
                int row = mt * 16 + l4 * 4 + r;
                fout[row * LDF + colbase + nt * 16 + l15] = acc[mt][nt][r] + bias[nt];
            }
    __syncthreads();

    const float4 gv = *(const float4*)(ln_g + 4 * lane);
    const float4 bv = *(const float4*)(ln_b + 4 * lane);
    for (int rr = 0; rr < 8; rr++) {
        const int row = w * 8 + rr;
        f32x4 v = *(const f32x4*)&fout[row * LDF + 4 * lane];
        float s1 = v[0] + v[1] + v[2] + v[3];
        float s2 = v[0] * v[0] + v[1] * v[1] + v[2] * v[2] + v[3] * v[3];
        #pragma unroll
        for (int o = 32; o > 0; o >>= 1) {
            s1 += __shfl_down(s1, o, 64);
            s2 += __shfl_down(s2, o, 64);
        }
        const float m = __shfl(s1, 0, 64) * (1.0f / (float)H);
        const float q = __shfl(s2, 0, 64) * (1.0f / (float)H);
        const float is = rsqrtf(fmaxf(q - m * m, 0.0f) + 1e-5f);
        float* dp = agg + (size_t)didx[row] * H + 4 * lane;
        atomicAdd(dp + 0, fmaxf((v[0] - m) * is * gv.x + bv.x, 0.0f));
        atomicAdd(dp + 1, fmaxf((v[1] - m) * is * gv.y + bv.y, 0.0f));
        atomicAdd(dp + 2, fmaxf((v[2] - m) * is * gv.z + bv.z, 0.0f));
        atomicAdd(dp + 3, fmaxf((v[3] - m) * is * gv.w + bv.w, 0.0f));
    }
    if (tid < EPB) {
        int d = didx[tid];
        atomicAdd(&cntw[d >> 2], 1u << ((d & 3) * 8));
    }
}

// ---------------- node phase: gate + GRU, M=64, staged bf16 weights --------
// 512 thr (8 waves). Wave w owns cols [w*32, w*32+32) of each output segment.
// SHH: W_hh staged as bf16 in ws (else f32-direct cvt8 fallback).
template<bool SHH>
__global__ __launch_bounds__(512, 2) void node_mfma(
    const float* __restrict__ node_emb, const float* __restrict__ h_prev,
    const unsigned short* __restrict__ WG, const float* __restrict__ b_gate,
    const float* __restrict__ lng_g, const float* __restrict__ lng_b,
    const unsigned short* __restrict__ WTih, const unsigned short* __restrict__ WThh,
    const float* __restrict__ Whh_f32,
    const float* __restrict__ b_ih, const float* __restrict__ b_hh,
    const float* __restrict__ lnr_g, const float* __restrict__ lnr_b,
    const unsigned int* __restrict__ cntw,
    float* __restrict__ out) {   // out holds agg (f32) on input
    __shared__ __align__(16) unsigned short Aga[NPB * LDA];  // 66,560 B: xn|en -> x -> f32 h
    __shared__ __align__(16) unsigned short shr[NPB * LDH];  // 33,792 B: u, then hp
    __shared__ float rc[NPB];

    const int tid = threadIdx.x;
    const int n0 = blockIdx.x * NPB;
    const int lane = tid & 63;
    const int w = tid >> 6;
    const int l15 = lane & 15, l4 = lane >> 4;

    if (tid < NPB) {
        int n = n0 + tid;
        float c = 1.0f;
        if (n < N_ENTS) {
            unsigned int cw = cntw[n >> 2];
            c = (float)((cw >> ((n & 3) * 8)) & 0xFFu);
        }
        rc[tid] = 1.0f / fmaxf(c, 1.0f);
    }
    __syncthreads();

    // ---- stage xn|en (Aga) as bf16, row-guarded ----
    for (int i = tid; i < NPB * 128; i += 512) {
        int row = i >> 7, c2 = (i & 127) * 2;
        int nr = n0 + row;
        size_t g = (size_t)(nr < N_ENTS ? nr : 0) * H + c2;
        float2 xv = *(const float2*)(node_emb + g);
        float2 ev = *(const float2*)(out + g);
        float r = rc[row];
        *(unsigned int*)&Aga[row * LDA + c2]       = pack2(xv.x, xv.y);
        *(unsigned int*)&Aga[row * LDA + 256 + c2] = pack2(ev.x * r, ev.y * r);
    }
    __syncthreads();

    // ---- gate GEMM: u[64x256] = [xn|en] @ W_gate, K=512 ----
    {
        f32x4 acc[4][2];
        #pragma unroll
        for (int m = 0; m < 4; m++)
            #pragma unroll
            for (int nt = 0; nt < 2; nt++) acc[m][nt] = (f32x4){0.f, 0.f, 0.f, 0.f};
        const unsigned short* Ab = &Aga[l15 * LDA + l4 * 8];
        const unsigned short* B0 = WG + (size_t)(w * 32 + l15) * (2 * H) + l4 * 8;
        const unsigned short* B1 = B0 + 16 * (2 * H);
        #pragma unroll 4
        for (int ks = 0; ks < 16; ks++) {
            const int o = ks * 32;
            bf16x8 b0 = __builtin_bit_cast(bf16x8, *(const uint4*)(B0 + o));
            bf16x8 b1 = __builtin_bit_cast(bf16x8, *(const uint4*)(B1 + o));
            #pragma unroll
            for (int m = 0; m < 4; m++) {
                bf16x8 a = __builtin_bit_cast(bf16x8, *(const uint4*)(Ab + m * 16 * LDA + o));
                acc[m][0] = __builtin_amdgcn_mfma_f32_16x16x32_bf16(a, b0, acc[m][0], 0, 0, 0);
                acc[m][1] = __builtin_amdgcn_mfma_f32_16x16x32_bf16(a, b1, acc[m][1], 0, 0, 0);
            }
        }
        const float bg0 = b_gate[w * 32 + l15];
        const float bg1 = b_gate[w * 32 + 16 + l15];
        #pragma unroll
        for (int m = 0; m < 4; m++)
            #pragma unroll
            for (int r = 0; r < 4; r++) {
                int row = m * 16 + l4 * 4 + r;
                shr[row * LDH + w * 32 + l15]      = f2b(acc[m][0][r] + bg0);
                shr[row * LDH + w * 32 + 16 + l15] = f2b(acc[m][1][r] + bg1);
            }
    }
    __syncthreads();

    // ---- gate epilogue: LN(u) -> sigmoid -> fused -> x (bf16 over Aga) ----
    {
        const float4 g4 = *(const float4*)(lng_g + 4 * lane);
        const float4 b4 = *(const float4*)(lng_b + 4 * lane);
        for (int rr = 0; rr < 8; rr++) {
            const int row = w * 8 + rr;
            short4 us = *(const short4*)&shr[row * LDH + 4 * lane];
            float u0 = u2f((unsigned short)us.x), u1 = u2f((unsigned short)us.y);
            float u2 = u2f((unsigned short)us.z), u3 = u2f((unsigned short)us.w);
            float s1 = u0 + u1 + u2 + u3;
            float s2 = u0 * u0 + u1 * u1 + u2 * u2 + u3 * u3;
            #pragma unroll
            for (int o = 32; o > 0; o >>= 1) {
                s1 += __shfl_down(s1, o, 64);
                s2 += __shfl_down(s2, o, 64);
            }
            const float m = __shfl(s1, 0, 64) * (1.0f / (float)H);
            const float q = __shfl(s2, 0, 64) * (1.0f / (float)H);
            const float is = rsqrtf(fmaxf(q - m * m, 0.0f) + 1e-5f);
            short4 xr = *(const short4*)&Aga[row * LDA + 4 * lane];
            short4 er = *(const short4*)&Aga[row * LDA + 256 + 4 * lane];
            float xv[4] = {u2f((unsigned short)xr.x), u2f((unsigned short)xr.y),
                           u2f((unsigned short)xr.z), u2f((unsigned short)xr.w)};
            float ev[4] = {u2f((unsigned short)er.x), u2f((unsigned short)er.y),
                           u2f((unsigned short)er.z), u2f((unsigned short)er.w)};
            float uu[4] = {u0, u1, u2, u3};
            float gl[4] = {g4.x, g4.y, g4.z, g4.w};
            float bl[4] = {b4.x, b4.y, b4.z, b4.w};
            unsigned short xs[4];
            #pragma unroll
            for (int j = 0; j < 4; j++) {
                float gate = sigm((uu[j] - m) * is * gl[j] + bl[j]);
                float fused = gate * xv[j] + (1.0f - gate) * ev[j];
                xs[j] = f2b(0.2f * xv[j] + 0.8f * fused);
            }
            *(unsigned int*)&Aga[row * LDA + 4 * lane]     = (unsigned int)xs[0] | ((unsigned int)xs[1] << 16);
            *(unsigned int*)&Aga[row * LDA + 4 * lane + 2] = (unsigned int)xs[2] | ((unsigned int)xs[3] << 16);
        }
    }
    __syncthreads();

    // ---- stage hp into shr (u is dead) ----
    for (int i = tid; i < NPB * 128; i += 512) {
        int row = i >> 7, c2 = (i & 127) * 2;
        int nr = n0 + row;
        size_t g = (size_t)(nr < N_ENTS ? nr : 0) * H + c2;
        float2 hv = *(const float2*)(h_prev + g);
        *(unsigned int*)&shr[row * LDH + c2] = pack2(hv.x, hv.y);
    }
    __syncthreads();

    // ---- GRU GEMMs: gi = x @ W_ih^T, gh = hp @ W_hh^T (bf16 B, staged) ----
    float hreg[2][4][4];
    #pragma unroll
    for (int p = 0; p < 2; p++) {
        f32x4 aI[3][4], aH[3][4];
        #pragma unroll
        for (int s = 0; s < 3; s++)
            #pragma unroll
            for (int m = 0; m < 4; m++) {
                aI[s][m] = (f32x4){0.f, 0.f, 0.f, 0.f};
                aH[s][m] = (f32x4){0.f, 0.f, 0.f, 0.f};
            }
        const int cl = w * 32 + p * 16 + l15;            // output col in [0,256)
        const unsigned short* Xb = &Aga[l15 * LDA + l4 * 8];
        const unsigned short* Pb = &shr[l15 * LDH + l4 * 8];
        const unsigned short* bi0 = WTih + (size_t)(cl) * H + l4 * 8;
        const unsigned short* bi1 = WTih + (size_t)(H + cl) * H + l4 * 8;
        const unsigned short* bi2 = WTih + (size_t)(2 * H + cl) * H + l4 * 8;
        const unsigned short* bh0s = WThh + (size_t)(cl) * H + l4 * 8;
        const unsigned short* bh1s = WThh + (size_t)(H + cl) * H + l4 * 8;
        const unsigned short* bh2s = WThh + (size_t)(2 * H + cl) * H + l4 * 8;
        const float* fh0 = Whh_f32 + (size_t)(cl) * H + l4 * 8;
        const float* fh1 = Whh_f32 + (size_t)(H + cl) * H + l4 * 8;
        const float* fh2 = Whh_f32 + (size_t)(2 * H + cl) * H + l4 * 8;
        #pragma unroll 4
        for (int ks = 0; ks < 8; ks++) {
            const int o = ks * 32;
            bf16x8 bI[3], bH[3];
            bI[0] = __builtin_bit_cast(bf16x8, *(const uint4*)(bi0 + o));
            bI[1] = __builtin_bit_cast(bf16x8, *(const uint4*)(bi1 + o));
            bI[2] = __builtin_bit_cast(bf16x8, *(const uint4*)(bi2 + o));
            if (SHH) {
                bH[0] = __builtin_bit_cast(bf16x8, *(const uint4*)(bh0s + o));
                bH[1] = __builtin_bit_cast(bf16x8, *(const uint4*)(bh1s + o));
                bH[2] = __builtin_bit_cast(bf16x8, *(const uint4*)(bh2s + o));
            } else {
                bH[0] = cvt8(fh0 + o);
                bH[1] = cvt8(fh1 + o);
                bH[2] = cvt8(fh2 + o);
            }
            #pragma unroll
            for (int m = 0; m < 4; m++) {
                bf16x8 ax = __builtin_bit_cast(bf16x8, *(const uint4*)(Xb + m * 16 * LDA + o));
                bf16x8 ah = __builtin_bit_cast(bf16x8, *(const uint4*)(Pb + m * 16 * LDH + o));
                #pragma unroll
                for (int s = 0; s < 3; s++) {
                    aI[s][m] = __builtin_amdgcn_mfma_f32_16x16x32_bf16(ax, bI[s], aI[s][m], 0, 0, 0);
                    aH[s][m] = __builtin_amdgcn_mfma_f32_16x16x32_bf16(ah, bH[s], aH[s][m], 0, 0, 0);
                }
            }
        }
        const float bi_0 = b_ih[cl], bi_1 = b_ih[H + cl], bi_2 = b_ih[2 * H + cl];
        const float bh_0 = b_hh[cl], bh_1 = b_hh[H + cl], bh_2 = b_hh[2 * H + cl];
        #pragma unroll
        for (int m = 0; m < 4; m++)
            #pragma unroll
            for (int r = 0; r < 4; r++) {
                const int row = m * 16 + l4 * 4 + r;
                int nr = n0 + row; if (nr >= N_ENTS) nr = N_ENTS - 1;
                float rg = sigm(aI[0][m][r] + bi_0 + aH[0][m][r] + bh_0);
                float zg = sigm(aI[1][m][r] + bi_1 + aH[1][m][r] + bh_1);
                float nn = tanhf(aI[2][m][r] + bi_2 + rg * (aH[2][m][r] + bh_2));
                float hpv = h_prev[(size_t)nr * H + cl];
                hreg[p][m][r] = (1.0f - zg) * nn + zg * hpv;
            }
    }
    __syncthreads();   // Aga (x) dead -> reuse as f32 h[64][260]

    float* hb = (float*)&Aga[0];
    #pragma unroll
    for (int p = 0; p < 2; p++) {
        const int cl = w * 32 + p * 16 + l15;
        #pragma unroll
        for (int m = 0; m < 4; m++)
            #pragma unroll
            for (int r = 0; r < 4; r++)
                hb[(m * 16 + l4 * 4 + r) * LDF2 + cl] = hreg[p][m][r];
    }
    __syncthreads();

    // ---- final LN + 0.3*h_prev residual ----
    {
        const float4 g4 = *(const float4*)(lnr_g + 4 * lane);
        const float4 b4 = *(const float4*)(lnr_b + 4 * lane);
        for (int rr = 0; rr < 8; rr++) {
            const int row = w * 8 + rr;
            const int nr = n0 + row;
            f32x4 hv = *(const f32x4*)&hb[row * LDF2 + 4 * lane];
            float s1 = hv[0] + hv[1] + hv[2] + hv[3];
            float s2 = hv[0] * hv[0] + hv[1] * hv[1] + hv[2] * hv[2] + hv[3] * hv[3];
            #pragma unroll
            for (int o = 32; o > 0; o >>= 1) {
                s1 += __shfl_down(s1, o, 64);
                s2 += __shfl_down(s2, o, 64);
            }
            const float m = __shfl(s1, 0, 64) * (1.0f / (float)H);
            const float q = __shfl(s2, 0, 64) * (1.0f / (float)H);
            const float is = rsqrtf(fmaxf(q - m * m, 0.0f) + 1e-5f);
            if (nr < N_ENTS) {
                const float4 hp4 = *(const float4*)(h_prev + (size_t)nr * H + 4 * lane);
                float4 o4;
                o4.x = (hv[0] - m) * is * g4.x + b4.x + 0.3f * hp4.x;
                o4.y = (hv[1] - m) * is * g4.y + b4.y + 0.3f * hp4.y;
                o4.z = (hv[2] - m) * is * g4.z + b4.z + 0.3f * hp4.z;
                o4.w = (hv[3] - m) * is * g4.w + b4.w + 0.3f * hp4.w;
                *(float4*)(out + (size_t)nr * H + 4 * lane) = o4;
            }
        }
    }
}

extern "C" void kernel_launch(void* const* d_in, const int* in_sizes, int n_in,
                              void* d_out, int out_size, void* d_ws, size_t ws_size,
                              hipStream_t stream) {
    (void)in_sizes; (void)n_in; (void)out_size;
    const float* node_emb  = (const float*)d_in[0];
    const float* h_prev    = (const float*)d_in[1];
    const float* type_emb  = (const float*)d_in[2];
    const float* W_edge    = (const float*)d_in[3];
    const float* b_edge    = (const float*)d_in[4];
    const float* ln_edge_g = (const float*)d_in[5];
    const float* ln_edge_b = (const float*)d_in[6];
    const float* W_gate    = (const float*)d_in[7];
    const float* b_gate    = (const float*)d_in[8];
    const float* ln_gate_g = (const float*)d_in[9];
    const float* ln_gate_b = (const float*)d_in[10];
    const float* W_ih      = (const float*)d_in[11];
    const float* W_hh      = (const float*)d_in[12];
    const float* b_ih      = (const float*)d_in[13];
    const float* b_hh      = (const float*)d_in[14];
    const float* ln_gru_g  = (const float*)d_in[15];
    const float* ln_gru_b  = (const float*)d_in[16];
    const int*   src       = (const int*)d_in[17];
    const int*   dst       = (const int*)d_in[18];
    const int*   et        = (const int*)d_in[19];
    float* out = (float*)d_out;

    // workspace layout:
    //   [0, 100000)         cnt u8-packed, 4/word
    //   [100000, 394912)    WE bf16 256x576   (edge phase only)
    //   [100000, 362144)    WG bf16 256x512   (node phase; overwrites WE)
    //   [362144, 755360)    WTih bf16 768x256 (node phase)
    //   [755360, 1148576)   WThh bf16 768x256 (only if ws_size allows)
    char* ws = (char*)d_ws;
    unsigned int* cntw  = (unsigned int*)ws;
    unsigned short* WE   = (unsigned short*)(ws + 100000);
    unsigned short* WG   = (unsigned short*)(ws + 100000);
    unsigned short* WTih = (unsigned short*)(ws + 362144);
    unsigned short* WThh = (unsigned short*)(ws + 755360);
    const bool big = ws_size >= (size_t)1148576;

    hipMemsetAsync(cntw, 0, 100000, stream);
    hipMemsetAsync(out, 0, (size_t)N_ENTS * H * sizeof(float), stream);

    hipLaunchKernelGGL(transpose_we, dim3(256), dim3(256), 0, stream, W_edge, WE);

    hipLaunchKernelGGL(edge_mfma, dim3(N_EDGES / EPB), dim3(256), 0, stream,
                       node_emb, type_emb, WE, b_edge, ln_edge_g, ln_edge_b,
                       src, dst, et, out, cntw);

    // WG/WTih overwrite the WE region -> must come after edge_mfma (stream order)
    hipLaunchKernelGGL(transpose_wg, dim3(256), dim3(256), 0, stream, W_gate, WG);
    hipLaunchKernelGGL(cast_gru, dim3(768), dim3(256), 0, stream,
                       W_ih, W_hh, WTih, WThh, big ? 1 : 0);

    const int nblocks = (N_ENTS + NPB - 1) / NPB;
    if (big) {
        hipLaunchKernelGGL((node_mfma<true>), dim3(nblocks), dim3(512), 0, stream,
                           node_emb, h_prev, WG, b_gate, ln_gate_g, ln_gate_b,
                           WTih, WThh, W_hh, b_ih, b_hh, ln_gru_g, ln_gru_b,
                           cntw, out);
    } else {
        hipLaunchKernelGGL((node_mfma<false>), dim3(nblocks), dim3(512), 0, stream,
                           node_emb, h_prev, WG, b_gate, ln_gate_g, ln_gate_b,
                           WTih, WTih /*unused*/, W_hh, b_ih, b_hh, ln_gru_g, ln_gru_b,
                           cntw, out);
    }
}

// Round 4
// 1027.223 us; speedup vs baseline: 2.6845x; 1.4030x over previous
//
#include <hip/hip_runtime.h>
#include <hip/hip_bf16.h>
#include <hip/hip_fp16.h>

#define H 256
#define TYPE_DIM 64
#define EIN (2*H + TYPE_DIM)   // 576
#define N_ENTS 100000
#define N_EDGES 200000
#define EPB 32                  // edges per block (MFMA M=32)
#define NPB 64                  // nodes per block (MFMA M=64, 4 m-frags/wave)
#define KE 576                  // K of edge GEMM
#define LDE 584                 // edge LDS row (bf16)
#define LDF 260                 // padded f32 row (edge epilogue)
#define LDA 520                 // node gate-A row (bf16): 512+8 (2-way bank alias = free)
#define LDH 264                 // u/hp rows (bf16): 256+8
#define LDF2 260                // f32 overlay stride (node final h)

typedef __hip_bfloat16 bf16;
typedef short bf16x8 __attribute__((ext_vector_type(8)));
typedef float f32x4 __attribute__((ext_vector_type(4)));

__device__ __forceinline__ unsigned short f2b(float f) {
    union { float f; unsigned int u; } v; v.f = f;
    unsigned int u = v.u;
    return (unsigned short)((u + 0x7FFFu + ((u >> 16) & 1u)) >> 16);
}
__device__ __forceinline__ unsigned int pack2(float a, float b) {
    return (unsigned int)f2b(a) | ((unsigned int)f2b(b) << 16);
}
__device__ __forceinline__ float u2f(unsigned short u) {
    union { unsigned int i; float f; } t; t.i = ((unsigned int)u) << 16; return t.f;
}
__device__ __forceinline__ float sigm(float x) { return 1.0f / (1.0f + __expf(-x)); }

// packed fp16 atomic add (2 halves per dword atomic), fire-and-forget
__device__ __forceinline__ void atomic_pk_f16(void* p, unsigned int v) {
    asm volatile("global_atomic_pk_add_f16 %0, %1, off" :: "v"(p), "v"(v) : "memory");
}

__device__ __forceinline__ bf16x8 cvt8(const float* p) {
    f32x4 a = *(const f32x4*)p;
    f32x4 b = *(const f32x4*)(p + 4);
    union { bf16 h[8]; bf16x8 v; } u;
    u.h[0] = __float2bfloat16(a[0]); u.h[1] = __float2bfloat16(a[1]);
    u.h[2] = __float2bfloat16(a[2]); u.h[3] = __float2bfloat16(a[3]);
    u.h[4] = __float2bfloat16(b[0]); u.h[5] = __float2bfloat16(b[1]);
    u.h[6] = __float2bfloat16(b[2]); u.h[7] = __float2bfloat16(b[3]);
    return u.v;
}

// ---------------- W_edge -> col-major bf16 (WE[c][k], row len 576) ---------
__global__ void transpose_we(const float* __restrict__ W,
                             unsigned short* __restrict__ WE) {
    int c = blockIdx.x;
    for (int j = threadIdx.x; j < KE; j += 256)
        WE[(size_t)c * KE + j] = f2b(W[(size_t)j * H + c]);
}

// ---------------- W_gate -> col-major bf16 (WG[c][k], row len 512) ---------
__global__ void transpose_wg(const float* __restrict__ W,
                             unsigned short* __restrict__ WG) {
    int c = blockIdx.x;
    for (int k = threadIdx.x; k < 2 * H; k += 256)
        WG[(size_t)c * (2 * H) + k] = f2b(W[(size_t)k * H + c]);
}

// ---------------- W_ih/W_hh f32 -> bf16 straight cast (layout kept) --------
__global__ void cast_gru(const float* __restrict__ Wih, const float* __restrict__ Whh,
                         unsigned short* __restrict__ WTih,
                         unsigned short* __restrict__ WThh, int do_hh) {
    int j = blockIdx.x;      // 0..767
    int k = threadIdx.x;     // 0..255
    WTih[(size_t)j * H + k] = f2b(Wih[(size_t)j * H + k]);
    if (do_hh) WThh[(size_t)j * H + k] = f2b(Whh[(size_t)j * H + k]);
}

// ---------------- edge MLP via MFMA + pk-f16 scatter ----------------------
// agg rows: fp16[256] (512 B) at the FIRST HALF of each 1 KB out-row slot.
__global__ __launch_bounds__(256) void edge_mfma(
    const float* __restrict__ node_emb, const float* __restrict__ type_emb,
    const unsigned short* __restrict__ WE,
    const float* __restrict__ b_edge,
    const float* __restrict__ ln_g, const float* __restrict__ ln_b,
    const int* __restrict__ src, const int* __restrict__ dst,
    const int* __restrict__ et,
    unsigned char* __restrict__ aggb,    // byte base of d_out
    unsigned int* __restrict__ cntw) {
    __shared__ __align__(16) unsigned short ein[EPB * LDE];
    __shared__ int sidx[EPB], didx[EPB], tidx[EPB];

    const int tid = threadIdx.x;
    const int e0 = blockIdx.x * EPB;
    const int lane = tid & 63;
    const int w = tid >> 6;
    const int l15 = lane & 15;
    const int l4 = lane >> 4;

    if (tid < EPB) {
        sidx[tid] = src[e0 + tid];
        didx[tid] = dst[e0 + tid];
        tidx[tid] = et[e0 + tid];
    }
    __syncthreads();

    {
        const int half = tid >> 7;
        const int tt = tid & 127;
        #pragma unroll 4
        for (int e = 0; e < EPB; e++) {
            const int n = half ? didx[e] : sidx[e];
            const float2 v = *(const float2*)(node_emb + (size_t)n * H + 2 * tt);
            *(unsigned int*)&ein[e * LDE + half * 256 + 2 * tt] = pack2(v.x, v.y);
        }
        #pragma unroll
        for (int i = tid; i < EPB * 32; i += 256) {
            const int e = i >> 5, j = i & 31;
            const float2 v = *(const float2*)(type_emb + (size_t)tidx[e] * TYPE_DIM + 2 * j);
            *(unsigned int*)&ein[e * LDE + 512 + 2 * j] = pack2(v.x, v.y);
        }
    }
    __syncthreads();

    f32x4 acc[2][4];
    #pragma unroll
    for (int mt = 0; mt < 2; mt++)
        #pragma unroll
        for (int nt = 0; nt < 4; nt++)
            acc[mt][nt] = (f32x4){0.f, 0.f, 0.f, 0.f};

    const int colbase = w * 64;
    const unsigned short* A0 = &ein[l15 * LDE + l4 * 8];
    const unsigned short* A1 = &ein[(16 + l15) * LDE + l4 * 8];
    const unsigned short* B0 = WE + (size_t)(colbase + l15) * KE + l4 * 8;
    const unsigned short* B1 = B0 + 16 * KE;
    const unsigned short* B2 = B0 + 32 * KE;
    const unsigned short* B3 = B0 + 48 * KE;

    for (int ks = 0; ks < KE / 32; ks++) {
        const int o = ks * 32;
        bf16x8 a0 = __builtin_bit_cast(bf16x8, *(const uint4*)(A0 + o));
        bf16x8 a1 = __builtin_bit_cast(bf16x8, *(const uint4*)(A1 + o));
        bf16x8 b0 = __builtin_bit_cast(bf16x8, *(const uint4*)(B0 + o));
        bf16x8 b1 = __builtin_bit_cast(bf16x8, *(const uint4*)(B1 + o));
        bf16x8 b2 = __builtin_bit_cast(bf16x8, *(const uint4*)(B2 + o));
        bf16x8 b3 = __builtin_bit_cast(bf16x8, *(const uint4*)(B3 + o));
        acc[0][0] = __builtin_amdgcn_mfma_f32_16x16x32_bf16(a0, b0, acc[0][0], 0, 0, 0);
        acc[0][1] = __builtin_amdgcn_mfma_f32_16x16x32_bf16(a0, b1, acc[0][1], 0, 0, 0);
        acc[0][2] = __builtin_amdgcn_mfma_f32_16x16x32_bf16(a0, b2, acc[0][2], 0, 0, 0);
        acc[0][3] = __builtin_amdgcn_mfma_f32_16x16x32_bf16(a0, b3, acc[0][3], 0, 0, 0);
        acc[1][0] = __builtin_amdgcn_mfma_f32_16x16x32_bf16(a1, b0, acc[1][0], 0, 0, 0);
        acc[1][1] = __builtin_amdgcn_mfma_f32_16x16x32_bf16(a1, b1, acc[1][1], 0, 0, 0);
        acc[1][2] = __builtin_amdgcn_mfma_f32_16x16x32_bf16(a1, b2, acc[1][2], 0, 0, 0);
        acc[1][3] = __builtin_amdgcn_mfma_f32_16x16x32_bf16(a1, b3, acc[1][3], 0, 0, 0);
    }

    __syncthreads();
    float* fout = (float*)&ein[0];

    float bias[4];
    #pragma unroll
    for (int nt = 0; nt < 4; nt++) bias[nt] = b_edge[colbase + nt * 16 + l15];
    #pragma unroll
    for (int mt = 0; mt < 2; mt++)
        #pragma unroll
        for (int nt = 0; nt < 4; nt++)
            #pragma unroll
            for (int r = 0; r < 4; r++) {
                int row = mt * 16 + l4 * 4 + r;
                fout[row * LDF + colbase + nt * 16 + l15] = acc[mt][nt][r] + bias[nt];
            }
    __syncthreads();

    const float4 gv = *(const float4*)(ln_g + 4 * lane);
    const float4 bv = *(const float4*)(ln_b + 4 * lane);
    for (int rr = 0; rr < 8; rr++) {
        const int row = w * 8 + rr;
        f32x4 v = *(const f32x4*)&fout[row * LDF + 4 * lane];
        float s1 = v[0] + v[1] + v[2] + v[3];
        float s2 = v[0] * v[0] + v[1] * v[1] + v[2] * v[2] + v[3] * v[3];
        #pragma unroll
        for (int o = 32; o > 0; o >>= 1) {
            s1 += __shfl_down(s1, o, 64);
            s2 += __shfl_down(s2, o, 64);
        }
        const float m = __shfl(s1, 0, 64) * (1.0f / (float)H);
        const float q = __shfl(s2, 0, 64) * (1.0f / (float)H);
        const float is = rsqrtf(fmaxf(q - m * m, 0.0f) + 1e-5f);
        float y0 = fmaxf((v[0] - m) * is * gv.x + bv.x, 0.0f);
        float y1 = fmaxf((v[1] - m) * is * gv.y + bv.y, 0.0f);
        float y2 = fmaxf((v[2] - m) * is * gv.z + bv.z, 0.0f);
        float y3 = fmaxf((v[3] - m) * is * gv.w + bv.w, 0.0f);
        __half2 h01 = __floats2half2_rn(y0, y1);
        __half2 h23 = __floats2half2_rn(y2, y3);
        unsigned char* dp = aggb + (size_t)didx[row] * 1024 + lane * 8;
        atomic_pk_f16(dp,     __builtin_bit_cast(unsigned int, h01));
        atomic_pk_f16(dp + 4, __builtin_bit_cast(unsigned int, h23));
    }
    if (tid < EPB) {
        int d = didx[tid];
        atomicAdd(&cntw[d >> 2], 1u << ((d & 3) * 8));
    }
}

// ---------------- node phase: gate + GRU, M=64, staged bf16 weights --------
template<bool SHH>
__global__ __launch_bounds__(512, 2) void node_mfma(
    const float* __restrict__ node_emb, const float* __restrict__ h_prev,
    const unsigned short* __restrict__ WG, const float* __restrict__ b_gate,
    const float* __restrict__ lng_g, const float* __restrict__ lng_b,
    const unsigned short* __restrict__ WTih, const unsigned short* __restrict__ WThh,
    const float* __restrict__ Whh_f32,
    const float* __restrict__ b_ih, const float* __restrict__ b_hh,
    const float* __restrict__ lnr_g, const float* __restrict__ lnr_b,
    const unsigned int* __restrict__ cntw,
    float* __restrict__ out) {   // out row slots hold fp16 agg (first 512 B) on input
    __shared__ __align__(16) unsigned short Aga[NPB * LDA];  // xn|en -> x -> f32 h
    __shared__ __align__(16) unsigned short shr[NPB * LDH];  // u, then hp
    __shared__ float rc[NPB];

    const int tid = threadIdx.x;
    const int n0 = blockIdx.x * NPB;
    const int lane = tid & 63;
    const int w = tid >> 6;
    const int l15 = lane & 15, l4 = lane >> 4;

    if (tid < NPB) {
        int n = n0 + tid;
        float c = 1.0f;
        if (n < N_ENTS) {
            unsigned int cw = cntw[n >> 2];
            c = (float)((cw >> ((n & 3) * 8)) & 0xFFu);
        }
        rc[tid] = 1.0f / fmaxf(c, 1.0f);
    }
    __syncthreads();

    const unsigned char* aggb = (const unsigned char*)out;

    // ---- stage xn|en (Aga) as bf16, row-guarded ----
    for (int i = tid; i < NPB * 128; i += 512) {
        int row = i >> 7, c2 = (i & 127) * 2;       // 2 cols per thread-iter
        int nr = n0 + row;
        size_t gn = (size_t)(nr < N_ENTS ? nr : 0);
        float2 xv = *(const float2*)(node_emb + gn * H + c2);
        unsigned int eu = *(const unsigned int*)(aggb + gn * 1024 + c2 * 2);
        float2 ev = __half22float2(__builtin_bit_cast(__half2, eu));
        float r = rc[row];
        *(unsigned int*)&Aga[row * LDA + c2]       = pack2(xv.x, xv.y);
        *(unsigned int*)&Aga[row * LDA + 256 + c2] = pack2(ev.x * r, ev.y * r);
    }
    __syncthreads();

    // ---- gate GEMM: u[64x256] = [xn|en] @ W_gate, K=512 ----
    {
        f32x4 acc[4][2];
        #pragma unroll
        for (int m = 0; m < 4; m++)
            #pragma unroll
            for (int nt = 0; nt < 2; nt++) acc[m][nt] = (f32x4){0.f, 0.f, 0.f, 0.f};
        const unsigned short* Ab = &Aga[l15 * LDA + l4 * 8];
        const unsigned short* B0 = WG + (size_t)(w * 32 + l15) * (2 * H) + l4 * 8;
        const unsigned short* B1 = B0 + 16 * (2 * H);
        #pragma unroll 4
        for (int ks = 0; ks < 16; ks++) {
            const int o = ks * 32;
            bf16x8 b0 = __builtin_bit_cast(bf16x8, *(const uint4*)(B0 + o));
            bf16x8 b1 = __builtin_bit_cast(bf16x8, *(const uint4*)(B1 + o));
            #pragma unroll
            for (int m = 0; m < 4; m++) {
                bf16x8 a = __builtin_bit_cast(bf16x8, *(const uint4*)(Ab + m * 16 * LDA + o));
                acc[m][0] = __builtin_amdgcn_mfma_f32_16x16x32_bf16(a, b0, acc[m][0], 0, 0, 0);
                acc[m][1] = __builtin_amdgcn_mfma_f32_16x16x32_bf16(a, b1, acc[m][1], 0, 0, 0);
            }
        }
        const float bg0 = b_gate[w * 32 + l15];
        const float bg1 = b_gate[w * 32 + 16 + l15];
        #pragma unroll
        for (int m = 0; m < 4; m++)
            #pragma unroll
            for (int r = 0; r < 4; r++) {
                int row = m * 16 + l4 * 4 + r;
                shr[row * LDH + w * 32 + l15]      = f2b(acc[m][0][r] + bg0);
                shr[row * LDH + w * 32 + 16 + l15] = f2b(acc[m][1][r] + bg1);
            }
    }
    __syncthreads();

    // ---- gate epilogue: LN(u) -> sigmoid -> fused -> x (bf16 over Aga) ----
    {
        const float4 g4 = *(const float4*)(lng_g + 4 * lane);
        const float4 b4 = *(const float4*)(lng_b + 4 * lane);
        for (int rr = 0; rr < 8; rr++) {
            const int row = w * 8 + rr;
            short4 us = *(const short4*)&shr[row * LDH + 4 * lane];
            float u0 = u2f((unsigned short)us.x), u1 = u2f((unsigned short)us.y);
            float u2 = u2f((unsigned short)us.z), u3 = u2f((unsigned short)us.w);
            float s1 = u0 + u1 + u2 + u3;
            float s2 = u0 * u0 + u1 * u1 + u2 * u2 + u3 * u3;
            #pragma unroll
            for (int o = 32; o > 0; o >>= 1) {
                s1 += __shfl_down(s1, o, 64);
                s2 += __shfl_down(s2, o, 64);
            }
            const float m = __shfl(s1, 0, 64) * (1.0f / (float)H);
            const float q = __shfl(s2, 0, 64) * (1.0f / (float)H);
            const float is = rsqrtf(fmaxf(q - m * m, 0.0f) + 1e-5f);
            short4 xr = *(const short4*)&Aga[row * LDA + 4 * lane];
            short4 er = *(const short4*)&Aga[row * LDA + 256 + 4 * lane];
            float xv[4] = {u2f((unsigned short)xr.x), u2f((unsigned short)xr.y),
                           u2f((unsigned short)xr.z), u2f((unsigned short)xr.w)};
            float ev[4] = {u2f((unsigned short)er.x), u2f((unsigned short)er.y),
                           u2f((unsigned short)er.z), u2f((unsigned short)er.w)};
            float uu[4] = {u0, u1, u2, u3};
            float gl[4] = {g4.x, g4.y, g4.z, g4.w};
            float bl[4] = {b4.x, b4.y, b4.z, b4.w};
            unsigned short xs[4];
            #pragma unroll
            for (int j = 0; j < 4; j++) {
                float gate = sigm((uu[j] - m) * is * gl[j] + bl[j]);
                float fused = gate * xv[j] + (1.0f - gate) * ev[j];
                xs[j] = f2b(0.2f * xv[j] + 0.8f * fused);
            }
            *(unsigned int*)&Aga[row * LDA + 4 * lane]     = (unsigned int)xs[0] | ((unsigned int)xs[1] << 16);
            *(unsigned int*)&Aga[row * LDA + 4 * lane + 2] = (unsigned int)xs[2] | ((unsigned int)xs[3] << 16);
        }
    }
    __syncthreads();

    // ---- stage hp into shr (u is dead) ----
    for (int i = tid; i < NPB * 128; i += 512) {
        int row = i >> 7, c2 = (i & 127) * 2;
        int nr = n0 + row;
        size_t g = (size_t)(nr < N_ENTS ? nr : 0) * H + c2;
        float2 hv = *(const float2*)(h_prev + g);
        *(unsigned int*)&shr[row * LDH + c2] = pack2(hv.x, hv.y);
    }
    __syncthreads();

    // ---- GRU GEMMs: gi = x @ W_ih^T, gh = hp @ W_hh^T (bf16 B, staged) ----
    float hreg[2][4][4];
    #pragma unroll
    for (int p = 0; p < 2; p++) {
        f32x4 aI[3][4], aH[3][4];
        #pragma unroll
        for (int s = 0; s < 3; s++)
            #pragma unroll
            for (int m = 0; m < 4; m++) {
                aI[s][m] = (f32x4){0.f, 0.f, 0.f, 0.f};
                aH[s][m] = (f32x4){0.f, 0.f, 0.f, 0.f};
            }
        const int cl = w * 32 + p * 16 + l15;
        const unsigned short* Xb = &Aga[l15 * LDA + l4 * 8];
        const unsigned short* Pb = &shr[l15 * LDH + l4 * 8];
        const unsigned short* bi0 = WTih + (size_t)(cl) * H + l4 * 8;
        const unsigned short* bi1 = WTih + (size_t)(H + cl) * H + l4 * 8;
        const unsigned short* bi2 = WTih + (size_t)(2 * H + cl) * H + l4 * 8;
        const unsigned short* bh0s = WThh + (size_t)(cl) * H + l4 * 8;
        const unsigned short* bh1s = WThh + (size_t)(H + cl) * H + l4 * 8;
        const unsigned short* bh2s = WThh + (size_t)(2 * H + cl) * H + l4 * 8;
        const float* fh0 = Whh_f32 + (size_t)(cl) * H + l4 * 8;
        const float* fh1 = Whh_f32 + (size_t)(H + cl) * H + l4 * 8;
        const float* fh2 = Whh_f32 + (size_t)(2 * H + cl) * H + l4 * 8;
        #pragma unroll 4
        for (int ks = 0; ks < 8; ks++) {
            const int o = ks * 32;
            bf16x8 bI[3], bH[3];
            bI[0] = __builtin_bit_cast(bf16x8, *(const uint4*)(bi0 + o));
            bI[1] = __builtin_bit_cast(bf16x8, *(const uint4*)(bi1 + o));
            bI[2] = __builtin_bit_cast(bf16x8, *(const uint4*)(bi2 + o));
            if (SHH) {
                bH[0] = __builtin_bit_cast(bf16x8, *(const uint4*)(bh0s + o));
                bH[1] = __builtin_bit_cast(bf16x8, *(const uint4*)(bh1s + o));
                bH[2] = __builtin_bit_cast(bf16x8, *(const uint4*)(bh2s + o));
            } else {
                bH[0] = cvt8(fh0 + o);
                bH[1] = cvt8(fh1 + o);
                bH[2] = cvt8(fh2 + o);
            }
            #pragma unroll
            for (int m = 0; m < 4; m++) {
                bf16x8 ax = __builtin_bit_cast(bf16x8, *(const uint4*)(Xb + m * 16 * LDA + o));
                bf16x8 ah = __builtin_bit_cast(bf16x8, *(const uint4*)(Pb + m * 16 * LDH + o));
                #pragma unroll
                for (int s = 0; s < 3; s++) {
                    aI[s][m] = __builtin_amdgcn_mfma_f32_16x16x32_bf16(ax, bI[s], aI[s][m], 0, 0, 0);
                    aH[s][m] = __builtin_amdgcn_mfma_f32_16x16x32_bf16(ah, bH[s], aH[s][m], 0, 0, 0);
                }
            }
        }
        const float bi_0 = b_ih[cl], bi_1 = b_ih[H + cl], bi_2 = b_ih[2 * H + cl];
        const float bh_0 = b_hh[cl], bh_1 = b_hh[H + cl], bh_2 = b_hh[2 * H + cl];
        #pragma unroll
        for (int m = 0; m < 4; m++)
            #pragma unroll
            for (int r = 0; r < 4; r++) {
                const int row = m * 16 + l4 * 4 + r;
                int nr = n0 + row; if (nr >= N_ENTS) nr = N_ENTS - 1;
                float rg = sigm(aI[0][m][r] + bi_0 + aH[0][m][r] + bh_0);
                float zg = sigm(aI[1][m][r] + bi_1 + aH[1][m][r] + bh_1);
                float nn = tanhf(aI[2][m][r] + bi_2 + rg * (aH[2][m][r] + bh_2));
                float hpv = h_prev[(size_t)nr * H + cl];
                hreg[p][m][r] = (1.0f - zg) * nn + zg * hpv;
            }
    }
    __syncthreads();   // Aga (x) dead -> reuse as f32 h[64][260]

    float* hb = (float*)&Aga[0];
    #pragma unroll
    for (int p = 0; p < 2; p++) {
        const int cl = w * 32 + p * 16 + l15;
        #pragma unroll
        for (int m = 0; m < 4; m++)
            #pragma unroll
            for (int r = 0; r < 4; r++)
                hb[(m * 16 + l4 * 4 + r) * LDF2 + cl] = hreg[p][m][r];
    }
    __syncthreads();

    // ---- final LN + 0.3*h_prev residual ----
    {
        const float4 g4 = *(const float4*)(lnr_g + 4 * lane);
        const float4 b4 = *(const float4*)(lnr_b + 4 * lane);
        for (int rr = 0; rr < 8; rr++) {
            const int row = w * 8 + rr;
            const int nr = n0 + row;
            f32x4 hv = *(const f32x4*)&hb[row * LDF2 + 4 * lane];
            float s1 = hv[0] + hv[1] + hv[2] + hv[3];
            float s2 = hv[0] * hv[0] + hv[1] * hv[1] + hv[2] * hv[2] + hv[3] * hv[3];
            #pragma unroll
            for (int o = 32; o > 0; o >>= 1) {
                s1 += __shfl_down(s1, o, 64);
                s2 += __shfl_down(s2, o, 64);
            }
            const float m = __shfl(s1, 0, 64) * (1.0f / (float)H);
            const float q = __shfl(s2, 0, 64) * (1.0f / (float)H);
            const float is = rsqrtf(fmaxf(q - m * m, 0.0f) + 1e-5f);
            if (nr < N_ENTS) {
                const float4 hp4 = *(const float4*)(h_prev + (size_t)nr * H + 4 * lane);
                float4 o4;
                o4.x = (hv[0] - m) * is * g4.x + b4.x + 0.3f * hp4.x;
                o4.y = (hv[1] - m) * is * g4.y + b4.y + 0.3f * hp4.y;
                o4.z = (hv[2] - m) * is * g4.z + b4.z + 0.3f * hp4.z;
                o4.w = (hv[3] - m) * is * g4.w + b4.w + 0.3f * hp4.w;
                *(float4*)(out + (size_t)nr * H + 4 * lane) = o4;
            }
        }
    }
}

extern "C" void kernel_launch(void* const* d_in, const int* in_sizes, int n_in,
                              void* d_out, int out_size, void* d_ws, size_t ws_size,
                              hipStream_t stream) {
    (void)in_sizes; (void)n_in; (void)out_size;
    const float* node_emb  = (const float*)d_in[0];
    const float* h_prev    = (const float*)d_in[1];
    const float* type_emb  = (const float*)d_in[2];
    const float* W_edge    = (const float*)d_in[3];
    const float* b_edge    = (const float*)d_in[4];
    const float* ln_edge_g = (const float*)d_in[5];
    const float* ln_edge_b = (const float*)d_in[6];
    const float* W_gate    = (const float*)d_in[7];
    const float* b_gate    = (const float*)d_in[8];
    const float* ln_gate_g = (const float*)d_in[9];
    const float* ln_gate_b = (const float*)d_in[10];
    const float* W_ih      = (const float*)d_in[11];
    const float* W_hh      = (const float*)d_in[12];
    const float* b_ih      = (const float*)d_in[13];
    const float* b_hh      = (const float*)d_in[14];
    const float* ln_gru_g  = (const float*)d_in[15];
    const float* ln_gru_b  = (const float*)d_in[16];
    const int*   src       = (const int*)d_in[17];
    const int*   dst       = (const int*)d_in[18];
    const int*   et        = (const int*)d_in[19];
    float* out = (float*)d_out;

    // workspace layout:
    //   [0, 100000)         cnt u8-packed, 4/word
    //   [100000, 394912)    WE bf16 256x576   (edge phase only)
    //   [100000, 362144)    WG bf16 256x512   (node phase; overwrites WE)
    //   [362144, 755360)    WTih bf16 768x256 (node phase)
    //   [755360, 1148576)   WThh bf16 768x256 (only if ws_size allows)
    char* ws = (char*)d_ws;
    unsigned int* cntw  = (unsigned int*)ws;
    unsigned short* WE   = (unsigned short*)(ws + 100000);
    unsigned short* WG   = (unsigned short*)(ws + 100000);
    unsigned short* WTih = (unsigned short*)(ws + 362144);
    unsigned short* WThh = (unsigned short*)(ws + 755360);
    const bool big = ws_size >= (size_t)1148576;

    hipMemsetAsync(cntw, 0, 100000, stream);
    // zero fp16 agg slots (first 512 B of each 1 KB out-row) — memset whole buffer
    hipMemsetAsync(out, 0, (size_t)N_ENTS * H * sizeof(float), stream);

    hipLaunchKernelGGL(transpose_we, dim3(256), dim3(256), 0, stream, W_edge, WE);

    hipLaunchKernelGGL(edge_mfma, dim3(N_EDGES / EPB), dim3(256), 0, stream,
                       node_emb, type_emb, WE, b_edge, ln_edge_g, ln_edge_b,
                       src, dst, et, (unsigned char*)out, cntw);

    hipLaunchKernelGGL(transpose_wg, dim3(256), dim3(256), 0, stream, W_gate, WG);
    hipLaunchKernelGGL(cast_gru, dim3(768), dim3(256), 0, stream,
                       W_ih, W_hh, WTih, WThh, big ? 1 : 0);

    const int nblocks = (N_ENTS + NPB - 1) / NPB;
    if (big) {
        hipLaunchKernelGGL((node_mfma<true>), dim3(nblocks), dim3(512), 0, stream,
                           node_emb, h_prev, WG, b_gate, ln_gate_g, ln_gate_b,
                           WTih, WThh, W_hh, b_ih, b_hh, ln_gru_g, ln_gru_b,
                           cntw, out);
    } else {
        hipLaunchKernelGGL((node_mfma<false>), dim3(nblocks), dim3(512), 0, stream,
                           node_emb, h_prev, WG, b_gate, ln_gate_g, ln_gate_b,
                           WTih, WTih /*unused*/, W_hh, b_ih, b_hh, ln_gru_g, ln_gru_b,
                           cntw, out);
    }
}

// Round 6
// 990.261 us; speedup vs baseline: 2.7847x; 1.0373x over previous
//
#include <hip/hip_runtime.h>
#include <hip/hip_bf16.h>
#include <hip/hip_fp16.h>

#define H 256
#define TYPE_DIM 64
#define EIN (2*H + TYPE_DIM)   // 576
#define N_ENTS 100000
#define N_EDGES 200000
#define EPB 32                  // edges per block (MFMA M=32)
#define NPB 64                  // nodes per block (MFMA M=64)
#define KE 576                  // K of edge GEMM
#define LDE 584                 // edge LDS row (bf16)
#define LDF 260                 // padded f32 row (edge epilogue)
#define LDA 520                 // node gate-A row (bf16): 512+8
#define LDH 264                 // u/hp rows (bf16): 256+8
#define LDF2 260                // f32 overlay stride (node final h)

typedef __hip_bfloat16 bf16;
typedef short bf16x8 __attribute__((ext_vector_type(8)));
typedef float f32x4 __attribute__((ext_vector_type(4)));

__device__ __forceinline__ unsigned short f2b(float f) {
    union { float f; unsigned int u; } v; v.f = f;
    unsigned int u = v.u;
    return (unsigned short)((u + 0x7FFFu + ((u >> 16) & 1u)) >> 16);
}
__device__ __forceinline__ unsigned int pack2(float a, float b) {
    return (unsigned int)f2b(a) | ((unsigned int)f2b(b) << 16);
}
__device__ __forceinline__ float u2f(unsigned short u) {
    union { unsigned int i; float f; } t; t.i = ((unsigned int)u) << 16; return t.f;
}
__device__ __forceinline__ float sigm(float x) { return 1.0f / (1.0f + __expf(-x)); }

__device__ __forceinline__ void atomic_pk_f16(void* p, unsigned int v) {
    asm volatile("global_atomic_pk_add_f16 %0, %1, off" :: "v"(p), "v"(v) : "memory");
}

__device__ __forceinline__ bf16x8 cvt8(const float* p) {
    f32x4 a = *(const f32x4*)p;
    f32x4 b = *(const f32x4*)(p + 4);
    union { bf16 h[8]; bf16x8 v; } u;
    u.h[0] = __float2bfloat16(a[0]); u.h[1] = __float2bfloat16(a[1]);
    u.h[2] = __float2bfloat16(a[2]); u.h[3] = __float2bfloat16(a[3]);
    u.h[4] = __float2bfloat16(b[0]); u.h[5] = __float2bfloat16(b[1]);
    u.h[6] = __float2bfloat16(b[2]); u.h[7] = __float2bfloat16(b[3]);
    return u.v;
}

// ---------------- W_edge -> col-major bf16 (WE[c][k], row len 576) ---------
__global__ void transpose_we(const float* __restrict__ W,
                             unsigned short* __restrict__ WE) {
    int c = blockIdx.x;
    for (int j = threadIdx.x; j < KE; j += 256)
        WE[(size_t)c * KE + j] = f2b(W[(size_t)j * H + c]);
}

// ---------------- W_gate -> col-major bf16 (WG[c][k], row len 512) ---------
__global__ void transpose_wg(const float* __restrict__ W,
                             unsigned short* __restrict__ WG) {
    int c = blockIdx.x;
    for (int k = threadIdx.x; k < 2 * H; k += 256)
        WG[(size_t)c * (2 * H) + k] = f2b(W[(size_t)k * H + c]);
}

// ---------------- W_ih/W_hh f32 -> bf16 straight cast (layout kept) --------
__global__ void cast_gru(const float* __restrict__ Wih, const float* __restrict__ Whh,
                         unsigned short* __restrict__ WTih,
                         unsigned short* __restrict__ WThh, int do_hh) {
    int j = blockIdx.x;
    int k = threadIdx.x;
    WTih[(size_t)j * H + k] = f2b(Wih[(size_t)j * H + k]);
    if (do_hh) WThh[(size_t)j * H + k] = f2b(Whh[(size_t)j * H + k]);
}

// ---------------- edge MLP via MFMA + pk-f16 scatter (unchanged) ----------
__global__ __launch_bounds__(256) void edge_mfma(
    const float* __restrict__ node_emb, const float* __restrict__ type_emb,
    const unsigned short* __restrict__ WE,
    const float* __restrict__ b_edge,
    const float* __restrict__ ln_g, const float* __restrict__ ln_b,
    const int* __restrict__ src, const int* __restrict__ dst,
    const int* __restrict__ et,
    unsigned char* __restrict__ aggb,
    unsigned int* __restrict__ cntw) {
    __shared__ __align__(16) unsigned short ein[EPB * LDE];
    __shared__ int sidx[EPB], didx[EPB], tidx[EPB];

    const int tid = threadIdx.x;
    const int e0 = blockIdx.x * EPB;
    const int lane = tid & 63;
    const int w = tid >> 6;
    const int l15 = lane & 15;
    const int l4 = lane >> 4;

    if (tid < EPB) {
        sidx[tid] = src[e0 + tid];
        didx[tid] = dst[e0 + tid];
        tidx[tid] = et[e0 + tid];
    }
    __syncthreads();

    {
        const int half = tid >> 7;
        const int tt = tid & 127;
        #pragma unroll 4
        for (int e = 0; e < EPB; e++) {
            const int n = half ? didx[e] : sidx[e];
            const float2 v = *(const float2*)(node_emb + (size_t)n * H + 2 * tt);
            *(unsigned int*)&ein[e * LDE + half * 256 + 2 * tt] = pack2(v.x, v.y);
        }
        #pragma unroll
        for (int i = tid; i < EPB * 32; i += 256) {
            const int e = i >> 5, j = i & 31;
            const float2 v = *(const float2*)(type_emb + (size_t)tidx[e] * TYPE_DIM + 2 * j);
            *(unsigned int*)&ein[e * LDE + 512 + 2 * j] = pack2(v.x, v.y);
        }
    }
    __syncthreads();

    f32x4 acc[2][4];
    #pragma unroll
    for (int mt = 0; mt < 2; mt++)
        #pragma unroll
        for (int nt = 0; nt < 4; nt++)
            acc[mt][nt] = (f32x4){0.f, 0.f, 0.f, 0.f};

    const int colbase = w * 64;
    const unsigned short* A0 = &ein[l15 * LDE + l4 * 8];
    const unsigned short* A1 = &ein[(16 + l15) * LDE + l4 * 8];
    const unsigned short* B0 = WE + (size_t)(colbase + l15) * KE + l4 * 8;
    const unsigned short* B1 = B0 + 16 * KE;
    const unsigned short* B2 = B0 + 32 * KE;
    const unsigned short* B3 = B0 + 48 * KE;

    for (int ks = 0; ks < KE / 32; ks++) {
        const int o = ks * 32;
        bf16x8 a0 = __builtin_bit_cast(bf16x8, *(const uint4*)(A0 + o));
        bf16x8 a1 = __builtin_bit_cast(bf16x8, *(const uint4*)(A1 + o));
        bf16x8 b0 = __builtin_bit_cast(bf16x8, *(const uint4*)(B0 + o));
        bf16x8 b1 = __builtin_bit_cast(bf16x8, *(const uint4*)(B1 + o));
        bf16x8 b2 = __builtin_bit_cast(bf16x8, *(const uint4*)(B2 + o));
        bf16x8 b3 = __builtin_bit_cast(bf16x8, *(const uint4*)(B3 + o));
        acc[0][0] = __builtin_amdgcn_mfma_f32_16x16x32_bf16(a0, b0, acc[0][0], 0, 0, 0);
        acc[0][1] = __builtin_amdgcn_mfma_f32_16x16x32_bf16(a0, b1, acc[0][1], 0, 0, 0);
        acc[0][2] = __builtin_amdgcn_mfma_f32_16x16x32_bf16(a0, b2, acc[0][2], 0, 0, 0);
        acc[0][3] = __builtin_amdgcn_mfma_f32_16x16x32_bf16(a0, b3, acc[0][3], 0, 0, 0);
        acc[1][0] = __builtin_amdgcn_mfma_f32_16x16x32_bf16(a1, b0, acc[1][0], 0, 0, 0);
        acc[1][1] = __builtin_amdgcn_mfma_f32_16x16x32_bf16(a1, b1, acc[1][1], 0, 0, 0);
        acc[1][2] = __builtin_amdgcn_mfma_f32_16x16x32_bf16(a1, b2, acc[1][2], 0, 0, 0);
        acc[1][3] = __builtin_amdgcn_mfma_f32_16x16x32_bf16(a1, b3, acc[1][3], 0, 0, 0);
    }

    __syncthreads();
    float* fout = (float*)&ein[0];

    float bias[4];
    #pragma unroll
    for (int nt = 0; nt < 4; nt++) bias[nt] = b_edge[colbase + nt * 16 + l15];
    #pragma unroll
    for (int mt = 0; mt < 2; mt++)
        #pragma unroll
        for (int nt = 0; nt < 4; nt++)
            #pragma unroll
            for (int r = 0; r < 4; r++) {
                int row = mt * 16 + l4 * 4 + r;
                fout[row * LDF + colbase + nt * 16 + l15] = acc[mt][nt][r] + bias[nt];
            }
    __syncthreads();

    const float4 gv = *(const float4*)(ln_g + 4 * lane);
    const float4 bv = *(const float4*)(ln_b + 4 * lane);
    for (int rr = 0; rr < 8; rr++) {
        const int row = w * 8 + rr;
        f32x4 v = *(const f32x4*)&fout[row * LDF + 4 * lane];
        float s1 = v[0] + v[1] + v[2] + v[3];
        float s2 = v[0] * v[0] + v[1] * v[1] + v[2] * v[2] + v[3] * v[3];
        #pragma unroll
        for (int o = 32; o > 0; o >>= 1) {
            s1 += __shfl_down(s1, o, 64);
            s2 += __shfl_down(s2, o, 64);
        }
        const float m = __shfl(s1, 0, 64) * (1.0f / (float)H);
        const float q = __shfl(s2, 0, 64) * (1.0f / (float)H);
        const float is = rsqrtf(fmaxf(q - m * m, 0.0f) + 1e-5f);
        float y0 = fmaxf((v[0] - m) * is * gv.x + bv.x, 0.0f);
        float y1 = fmaxf((v[1] - m) * is * gv.y + bv.y, 0.0f);
        float y2 = fmaxf((v[2] - m) * is * gv.z + bv.z, 0.0f);
        float y3 = fmaxf((v[3] - m) * is * gv.w + bv.w, 0.0f);
        __half2 h01 = __floats2half2_rn(y0, y1);
        __half2 h23 = __floats2half2_rn(y2, y3);
        unsigned char* dp = aggb + (size_t)didx[row] * 1024 + lane * 8;
        atomic_pk_f16(dp,     __builtin_bit_cast(unsigned int, h01));
        atomic_pk_f16(dp + 4, __builtin_bit_cast(unsigned int, h23));
    }
    if (tid < EPB) {
        int d = didx[tid];
        atomicAdd(&cntw[d >> 2], 1u << ((d & 3) * 8));
    }
}

// ---------------- node phase: 1024 thr (16 waves), M=64, 16 cols/wave ------
template<bool SHH>
__global__ __launch_bounds__(1024, 4) void node_mfma(
    const float* __restrict__ node_emb, const float* __restrict__ h_prev,
    const unsigned short* __restrict__ WG, const float* __restrict__ b_gate,
    const float* __restrict__ lng_g, const float* __restrict__ lng_b,
    const unsigned short* __restrict__ WTih, const unsigned short* __restrict__ WThh,
    const float* __restrict__ Whh_f32,
    const float* __restrict__ b_ih, const float* __restrict__ b_hh,
    const float* __restrict__ lnr_g, const float* __restrict__ lnr_b,
    const unsigned int* __restrict__ cntw,
    float* __restrict__ out) {   // out row slots hold fp16 agg (first 512 B)
    __shared__ __align__(16) unsigned short Aga[NPB * LDA];  // xn|en -> x -> f32 h
    __shared__ __align__(16) unsigned short shr[NPB * LDH];  // u, then hp
    __shared__ float rc[NPB];

    const int tid = threadIdx.x;
    const int n0 = blockIdx.x * NPB;
    const int lane = tid & 63;
    const int w = tid >> 6;          // 0..15, wave w owns cols [w*16, w*16+16)
    const int l15 = lane & 15, l4 = lane >> 4;

    if (tid < NPB) {
        int n = n0 + tid;
        float c = 1.0f;
        if (n < N_ENTS) {
            unsigned int cw = cntw[n >> 2];
            c = (float)((cw >> ((n & 3) * 8)) & 0xFFu);
        }
        rc[tid] = 1.0f / fmaxf(c, 1.0f);
    }
    __syncthreads();

    const unsigned char* aggb = (const unsigned char*)out;

    // ---- stage xn|en (Aga) as bf16 ----
    for (int i = tid; i < NPB * 128; i += 1024) {
        int row = i >> 7, c2 = (i & 127) * 2;
        int nr = n0 + row;
        size_t gn = (size_t)(nr < N_ENTS ? nr : 0);
        float2 xv = *(const float2*)(node_emb + gn * H + c2);
        unsigned int eu = *(const unsigned int*)(aggb + gn * 1024 + c2 * 2);
        float2 ev = __half22float2(__builtin_bit_cast(__half2, eu));
        float r = rc[row];
        *(unsigned int*)&Aga[row * LDA + c2]       = pack2(xv.x, xv.y);
        *(unsigned int*)&Aga[row * LDA + 256 + c2] = pack2(ev.x * r, ev.y * r);
    }
    __syncthreads();

    // ---- gate GEMM: u[64x256] = [xn|en] @ W_gate, K=512; 16 cols/wave ----
    {
        f32x4 acc[4];
        #pragma unroll
        for (int m = 0; m < 4; m++) acc[m] = (f32x4){0.f, 0.f, 0.f, 0.f};
        const unsigned short* Ab = &Aga[l15 * LDA + l4 * 8];
        const unsigned short* B0 = WG + (size_t)(w * 16 + l15) * (2 * H) + l4 * 8;
        #pragma unroll 4
        for (int ks = 0; ks < 16; ks++) {
            const int o = ks * 32;
            bf16x8 b0 = __builtin_bit_cast(bf16x8, *(const uint4*)(B0 + o));
            #pragma unroll
            for (int m = 0; m < 4; m++) {
                bf16x8 a = __builtin_bit_cast(bf16x8, *(const uint4*)(Ab + m * 16 * LDA + o));
                acc[m] = __builtin_amdgcn_mfma_f32_16x16x32_bf16(a, b0, acc[m], 0, 0, 0);
            }
        }
        const float bg0 = b_gate[w * 16 + l15];
        #pragma unroll
        for (int m = 0; m < 4; m++)
            #pragma unroll
            for (int r = 0; r < 4; r++) {
                int row = m * 16 + l4 * 4 + r;
                shr[row * LDH + w * 16 + l15] = f2b(acc[m][r] + bg0);
            }
    }
    __syncthreads();

    // ---- gate epilogue: LN(u) -> sigmoid -> fused -> x; 4 rows/wave ----
    {
        const float4 g4 = *(const float4*)(lng_g + 4 * lane);
        const float4 b4 = *(const float4*)(lng_b + 4 * lane);
        for (int rr = 0; rr < 4; rr++) {
            const int row = w * 4 + rr;
            short4 us = *(const short4*)&shr[row * LDH + 4 * lane];
            float u0 = u2f((unsigned short)us.x), u1 = u2f((unsigned short)us.y);
            float u2 = u2f((unsigned short)us.z), u3 = u2f((unsigned short)us.w);
            float s1 = u0 + u1 + u2 + u3;
            float s2 = u0 * u0 + u1 * u1 + u2 * u2 + u3 * u3;
            #pragma unroll
            for (int o = 32; o > 0; o >>= 1) {
                s1 += __shfl_down(s1, o, 64);
                s2 += __shfl_down(s2, o, 64);
            }
            const float m = __shfl(s1, 0, 64) * (1.0f / (float)H);
            const float q = __shfl(s2, 0, 64) * (1.0f / (float)H);
            const float is = rsqrtf(fmaxf(q - m * m, 0.0f) + 1e-5f);
            short4 xr = *(const short4*)&Aga[row * LDA + 4 * lane];
            short4 er = *(const short4*)&Aga[row * LDA + 256 + 4 * lane];
            float xv[4] = {u2f((unsigned short)xr.x), u2f((unsigned short)xr.y),
                           u2f((unsigned short)xr.z), u2f((unsigned short)xr.w)};
            float ev[4] = {u2f((unsigned short)er.x), u2f((unsigned short)er.y),
                           u2f((unsigned short)er.z), u2f((unsigned short)er.w)};
            float uu[4] = {u0, u1, u2, u3};
            float gl[4] = {g4.x, g4.y, g4.z, g4.w};
            float bl[4] = {b4.x, b4.y, b4.z, b4.w};
            unsigned short xs[4];
            #pragma unroll
            for (int j = 0; j < 4; j++) {
                float gate = sigm((uu[j] - m) * is * gl[j] + bl[j]);
                float fused = gate * xv[j] + (1.0f - gate) * ev[j];
                xs[j] = f2b(0.2f * xv[j] + 0.8f * fused);
            }
            *(unsigned int*)&Aga[row * LDA + 4 * lane]     = (unsigned int)xs[0] | ((unsigned int)xs[1] << 16);
            *(unsigned int*)&Aga[row * LDA + 4 * lane + 2] = (unsigned int)xs[2] | ((unsigned int)xs[3] << 16);
        }
    }
    __syncthreads();

    // ---- stage hp into shr (u dead) ----
    for (int i = tid; i < NPB * 128; i += 1024) {
        int row = i >> 7, c2 = (i & 127) * 2;
        int nr = n0 + row;
        size_t g = (size_t)(nr < N_ENTS ? nr : 0) * H + c2;
        float2 hv = *(const float2*)(h_prev + g);
        *(unsigned int*)&shr[row * LDH + c2] = pack2(hv.x, hv.y);
    }
    __syncthreads();

    // ---- GRU, two K-passes to bound VGPR: pass1 = r,z; pass2 = n ----
    const int cl = w * 16 + l15;     // output col in [0,256)
    const unsigned short* Xb = &Aga[l15 * LDA + l4 * 8];
    const unsigned short* Pb = &shr[l15 * LDH + l4 * 8];

    float rg[4][4], zg[4][4];
    {
        f32x4 aIr[4], aIz[4], aHr[4], aHz[4];
        #pragma unroll
        for (int m = 0; m < 4; m++) {
            aIr[m] = (f32x4){0.f, 0.f, 0.f, 0.f}; aIz[m] = (f32x4){0.f, 0.f, 0.f, 0.f};
            aHr[m] = (f32x4){0.f, 0.f, 0.f, 0.f}; aHz[m] = (f32x4){0.f, 0.f, 0.f, 0.f};
        }
        const unsigned short* bi0 = WTih + (size_t)(cl) * H + l4 * 8;
        const unsigned short* bi1 = WTih + (size_t)(H + cl) * H + l4 * 8;
        const unsigned short* bh0s = WThh + (size_t)(cl) * H + l4 * 8;
        const unsigned short* bh1s = WThh + (size_t)(H + cl) * H + l4 * 8;
        const float* fh0 = Whh_f32 + (size_t)(cl) * H + l4 * 8;
        const float* fh1 = Whh_f32 + (size_t)(H + cl) * H + l4 * 8;
        #pragma unroll 4
        for (int ks = 0; ks < 8; ks++) {
            const int o = ks * 32;
            bf16x8 vI0 = __builtin_bit_cast(bf16x8, *(const uint4*)(bi0 + o));
            bf16x8 vI1 = __builtin_bit_cast(bf16x8, *(const uint4*)(bi1 + o));
            bf16x8 vH0, vH1;
            if (SHH) {
                vH0 = __builtin_bit_cast(bf16x8, *(const uint4*)(bh0s + o));
                vH1 = __builtin_bit_cast(bf16x8, *(const uint4*)(bh1s + o));
            } else {
                vH0 = cvt8(fh0 + o);
                vH1 = cvt8(fh1 + o);
            }
            #pragma unroll
            for (int m = 0; m < 4; m++) {
                bf16x8 ax = __builtin_bit_cast(bf16x8, *(const uint4*)(Xb + m * 16 * LDA + o));
                bf16x8 ah = __builtin_bit_cast(bf16x8, *(const uint4*)(Pb + m * 16 * LDH + o));
                aIr[m] = __builtin_amdgcn_mfma_f32_16x16x32_bf16(ax, vI0, aIr[m], 0, 0, 0);
                aIz[m] = __builtin_amdgcn_mfma_f32_16x16x32_bf16(ax, vI1, aIz[m], 0, 0, 0);
                aHr[m] = __builtin_amdgcn_mfma_f32_16x16x32_bf16(ah, vH0, aHr[m], 0, 0, 0);
                aHz[m] = __builtin_amdgcn_mfma_f32_16x16x32_bf16(ah, vH1, aHz[m], 0, 0, 0);
            }
        }
        const float bi_0 = b_ih[cl], bi_1 = b_ih[H + cl];
        const float bh_0 = b_hh[cl], bh_1 = b_hh[H + cl];
        #pragma unroll
        for (int m = 0; m < 4; m++)
            #pragma unroll
            for (int r = 0; r < 4; r++) {
                rg[m][r] = sigm(aIr[m][r] + bi_0 + aHr[m][r] + bh_0);
                zg[m][r] = sigm(aIz[m][r] + bi_1 + aHz[m][r] + bh_1);
            }
    }

    float hreg[4][4];
    {
        f32x4 aIn[4], aHn[4];
        #pragma unroll
        for (int m = 0; m < 4; m++) {
            aIn[m] = (f32x4){0.f, 0.f, 0.f, 0.f};
            aHn[m] = (f32x4){0.f, 0.f, 0.f, 0.f};
        }
        const unsigned short* bi2 = WTih + (size_t)(2 * H + cl) * H + l4 * 8;
        const unsigned short* bh2s = WThh + (size_t)(2 * H + cl) * H + l4 * 8;
        const float* fh2 = Whh_f32 + (size_t)(2 * H + cl) * H + l4 * 8;
        #pragma unroll 4
        for (int ks = 0; ks < 8; ks++) {
            const int o = ks * 32;
            bf16x8 vI2 = __builtin_bit_cast(bf16x8, *(const uint4*)(bi2 + o));
            bf16x8 vH2;
            if (SHH) vH2 = __builtin_bit_cast(bf16x8, *(const uint4*)(bh2s + o));
            else     vH2 = cvt8(fh2 + o);
            #pragma unroll
            for (int m = 0; m < 4; m++) {
                bf16x8 ax = __builtin_bit_cast(bf16x8, *(const uint4*)(Xb + m * 16 * LDA + o));
                bf16x8 ah = __builtin_bit_cast(bf16x8, *(const uint4*)(Pb + m * 16 * LDH + o));
                aIn[m] = __builtin_amdgcn_mfma_f32_16x16x32_bf16(ax, vI2, aIn[m], 0, 0, 0);
                aHn[m] = __builtin_amdgcn_mfma_f32_16x16x32_bf16(ah, vH2, aHn[m], 0, 0, 0);
            }
        }
        const float bi_2 = b_ih[2 * H + cl];
        const float bh_2 = b_hh[2 * H + cl];
        #pragma unroll
        for (int m = 0; m < 4; m++)
            #pragma unroll
            for (int r = 0; r < 4; r++) {
                const int row = m * 16 + l4 * 4 + r;
                int nr = n0 + row; if (nr >= N_ENTS) nr = N_ENTS - 1;
                float nn = tanhf(aIn[m][r] + bi_2 + rg[m][r] * (aHn[m][r] + bh_2));
                float hpv = h_prev[(size_t)nr * H + cl];
                hreg[m][r] = (1.0f - zg[m][r]) * nn + zg[m][r] * hpv;
            }
    }
    __syncthreads();   // Aga dead -> reuse as f32 h[64][260]

    float* hb = (float*)&Aga[0];
    #pragma unroll
    for (int m = 0; m < 4; m++)
        #pragma unroll
        for (int r = 0; r < 4; r++)
            hb[(m * 16 + l4 * 4 + r) * LDF2 + cl] = hreg[m][r];
    __syncthreads();

    // ---- final LN + 0.3*h_prev residual; 4 rows/wave ----
    {
        const float4 g4 = *(const float4*)(lnr_g + 4 * lane);
        const float4 b4 = *(const float4*)(lnr_b + 4 * lane);
        for (int rr = 0; rr < 4; rr++) {
            const int row = w * 4 + rr;
            const int nr = n0 + row;
            f32x4 hv = *(const f32x4*)&hb[row * LDF2 + 4 * lane];
            float s1 = hv[0] + hv[1] + hv[2] + hv[3];
            float s2 = hv[0] * hv[0] + hv[1] * hv[1] + hv[2] * hv[2] + hv[3] * hv[3];
            #pragma unroll
            for (int o = 32; o > 0; o >>= 1) {
                s1 += __shfl_down(s1, o, 64);
                s2 += __shfl_down(s2, o, 64);
            }
            const float m = __shfl(s1, 0, 64) * (1.0f / (float)H);
            const float q = __shfl(s2, 0, 64) * (1.0f / (float)H);
            const float is = rsqrtf(fmaxf(q - m * m, 0.0f) + 1e-5f);
            if (nr < N_ENTS) {
                const float4 hp4 = *(const float4*)(h_prev + (size_t)nr * H + 4 * lane);
                float4 o4;
                o4.x = (hv[0] - m) * is * g4.x + b4.x + 0.3f * hp4.x;
                o4.y = (hv[1] - m) * is * g4.y + b4.y + 0.3f * hp4.y;
                o4.z = (hv[2] - m) * is * g4.z + b4.z + 0.3f * hp4.z;
                o4.w = (hv[3] - m) * is * g4.w + b4.w + 0.3f * hp4.w;
                *(float4*)(out + (size_t)nr * H + 4 * lane) = o4;
            }
        }
    }
}

extern "C" void kernel_launch(void* const* d_in, const int* in_sizes, int n_in,
                              void* d_out, int out_size, void* d_ws, size_t ws_size,
                              hipStream_t stream) {
    (void)in_sizes; (void)n_in; (void)out_size;
    const float* node_emb  = (const float*)d_in[0];
    const float* h_prev    = (const float*)d_in[1];
    const float* type_emb  = (const float*)d_in[2];
    const float* W_edge    = (const float*)d_in[3];
    const float* b_edge    = (const float*)d_in[4];
    const float* ln_edge_g = (const float*)d_in[5];
    const float* ln_edge_b = (const float*)d_in[6];
    const float* W_gate    = (const float*)d_in[7];
    const float* b_gate    = (const float*)d_in[8];
    const float* ln_gate_g = (const float*)d_in[9];
    const float* ln_gate_b = (const float*)d_in[10];
    const float* W_ih      = (const float*)d_in[11];
    const float* W_hh      = (const float*)d_in[12];
    const float* b_ih      = (const float*)d_in[13];
    const float* b_hh      = (const float*)d_in[14];
    const float* ln_gru_g  = (const float*)d_in[15];
    const float* ln_gru_b  = (const float*)d_in[16];
    const int*   src       = (const int*)d_in[17];
    const int*   dst       = (const int*)d_in[18];
    const int*   et        = (const int*)d_in[19];
    float* out = (float*)d_out;

    // workspace layout:
    //   [0, 100000)         cnt u8-packed, 4/word
    //   [100000, 394912)    WE bf16 256x576   (edge phase only)
    //   [100000, 362144)    WG bf16 256x512   (node phase; overwrites WE)
    //   [362144, 755360)    WTih bf16 768x256 (node phase)
    //   [755360, 1148576)   WThh bf16 768x256 (only if ws_size allows)
    char* ws = (char*)d_ws;
    unsigned int* cntw  = (unsigned int*)ws;
    unsigned short* WE   = (unsigned short*)(ws + 100000);
    unsigned short* WG   = (unsigned short*)(ws + 100000);
    unsigned short* WTih = (unsigned short*)(ws + 362144);
    unsigned short* WThh = (unsigned short*)(ws + 755360);
    const bool big = ws_size >= (size_t)1148576;

    hipMemsetAsync(cntw, 0, 100000, stream);
    hipMemsetAsync(out, 0, (size_t)N_ENTS * H * sizeof(float), stream);

    hipLaunchKernelGGL(transpose_we, dim3(256), dim3(256), 0, stream, W_edge, WE);

    hipLaunchKernelGGL(edge_mfma, dim3(N_EDGES / EPB), dim3(256), 0, stream,
                       node_emb, type_emb, WE, b_edge, ln_edge_g, ln_edge_b,
                       src, dst, et, (unsigned char*)out, cntw);

    hipLaunchKernelGGL(transpose_wg, dim3(256), dim3(256), 0, stream, W_gate, WG);
    hipLaunchKernelGGL(cast_gru, dim3(768), dim3(256), 0, stream,
                       W_ih, W_hh, WTih, WThh, big ? 1 : 0);

    const int nblocks = (N_ENTS + NPB - 1) / NPB;
    if (big) {
        hipLaunchKernelGGL((node_mfma<true>), dim3(nblocks), dim3(1024), 0, stream,
                           node_emb, h_prev, WG, b_gate, ln_gate_g, ln_gate_b,
                           WTih, WThh, W_hh, b_ih, b_hh, ln_gru_g, ln_gru_b,
                           cntw, out);
    } else {
        hipLaunchKernelGGL((node_mfma<false>), dim3(nblocks), dim3(1024), 0, stream,
                           node_emb, h_prev, WG, b_gate, ln_gate_g, ln_gate_b,
                           WTih, WTih /*unused*/, W_hh, b_ih, b_hh, ln_gru_g, ln_gru_b,
                           cntw, out);
    }
}

// Round 7
// 968.266 us; speedup vs baseline: 2.8479x; 1.0227x over previous
//
#include <hip/hip_runtime.h>
#include <hip/hip_bf16.h>
#include <hip/hip_fp16.h>

#define H 256
#define TYPE_DIM 64
#define EIN (2*H + TYPE_DIM)   // 576
#define N_ENTS 100000
#define N_EDGES 200000
#define EPB 32                  // edges per block (MFMA M=32)
#define NPB 64                  // nodes per block (MFMA M=64)
#define KE 576                  // K of edge GEMM
#define LDE 584                 // edge LDS row (bf16)
#define LDF 260                 // padded f32 row (edge epilogue)

typedef __hip_bfloat16 bf16;
typedef short bf16x8 __attribute__((ext_vector_type(8)));
typedef float f32x4 __attribute__((ext_vector_type(4)));

__device__ __forceinline__ unsigned short f2b(float f) {
    union { float f; unsigned int u; } v; v.f = f;
    unsigned int u = v.u;
    return (unsigned short)((u + 0x7FFFu + ((u >> 16) & 1u)) >> 16);
}
__device__ __forceinline__ unsigned int pack2(float a, float b) {
    return (unsigned int)f2b(a) | ((unsigned int)f2b(b) << 16);
}
__device__ __forceinline__ float u2f(unsigned short u) {
    union { unsigned int i; float f; } t; t.i = ((unsigned int)u) << 16; return t.f;
}
__device__ __forceinline__ float sigm(float x) { return 1.0f / (1.0f + __expf(-x)); }

__device__ __forceinline__ void atomic_pk_f16(void* p, unsigned int v) {
    asm volatile("global_atomic_pk_add_f16 %0, %1, off" :: "v"(p), "v"(v) : "memory");
}

__device__ __forceinline__ bf16x8 cvt8(const float* p) {
    f32x4 a = *(const f32x4*)p;
    f32x4 b = *(const f32x4*)(p + 4);
    union { bf16 h[8]; bf16x8 v; } u;
    u.h[0] = __float2bfloat16(a[0]); u.h[1] = __float2bfloat16(a[1]);
    u.h[2] = __float2bfloat16(a[2]); u.h[3] = __float2bfloat16(a[3]);
    u.h[4] = __float2bfloat16(b[0]); u.h[5] = __float2bfloat16(b[1]);
    u.h[6] = __float2bfloat16(b[2]); u.h[7] = __float2bfloat16(b[3]);
    return u.v;
}

// swizzled LDS A-fragment read: 16B at (row*stride + kbyte) ^ ((row&7)<<4)
__device__ __forceinline__ bf16x8 ldsA(const char* base, int row, int kbyte, int stride) {
    return __builtin_bit_cast(bf16x8,
        *(const uint4*)(base + (((row * stride) + kbyte) ^ ((row & 7) << 4))));
}

// ---------------- W_edge -> col-major bf16 (WE[c][k], row len 576) ---------
__global__ void transpose_we(const float* __restrict__ W,
                             unsigned short* __restrict__ WE) {
    int c = blockIdx.x;
    for (int j = threadIdx.x; j < KE; j += 256)
        WE[(size_t)c * KE + j] = f2b(W[(size_t)j * H + c]);
}

// ---------------- W_gate -> col-major bf16 (WG[c][k], row len 512) ---------
__global__ void transpose_wg(const float* __restrict__ W,
                             unsigned short* __restrict__ WG) {
    int c = blockIdx.x;
    for (int k = threadIdx.x; k < 2 * H; k += 256)
        WG[(size_t)c * (2 * H) + k] = f2b(W[(size_t)k * H + c]);
}

// ---------------- W_ih/W_hh f32 -> bf16 straight cast (layout kept) --------
__global__ void cast_gru(const float* __restrict__ Wih, const float* __restrict__ Whh,
                         unsigned short* __restrict__ WTih,
                         unsigned short* __restrict__ WThh, int do_hh) {
    int j = blockIdx.x;
    int k = threadIdx.x;
    WTih[(size_t)j * H + k] = f2b(Wih[(size_t)j * H + k]);
    if (do_hh) WThh[(size_t)j * H + k] = f2b(Whh[(size_t)j * H + k]);
}

// ---------------- edge MLP via MFMA + pk-f16 scatter (unchanged) ----------
__global__ __launch_bounds__(256) void edge_mfma(
    const float* __restrict__ node_emb, const float* __restrict__ type_emb,
    const unsigned short* __restrict__ WE,
    const float* __restrict__ b_edge,
    const float* __restrict__ ln_g, const float* __restrict__ ln_b,
    const int* __restrict__ src, const int* __restrict__ dst,
    const int* __restrict__ et,
    unsigned char* __restrict__ aggb,
    unsigned int* __restrict__ cntw) {
    __shared__ __align__(16) unsigned short ein[EPB * LDE];
    __shared__ int sidx[EPB], didx[EPB], tidx[EPB];

    const int tid = threadIdx.x;
    const int e0 = blockIdx.x * EPB;
    const int lane = tid & 63;
    const int w = tid >> 6;
    const int l15 = lane & 15;
    const int l4 = lane >> 4;

    if (tid < EPB) {
        sidx[tid] = src[e0 + tid];
        didx[tid] = dst[e0 + tid];
        tidx[tid] = et[e0 + tid];
    }
    __syncthreads();

    {
        const int half = tid >> 7;
        const int tt = tid & 127;
        #pragma unroll 4
        for (int e = 0; e < EPB; e++) {
            const int n = half ? didx[e] : sidx[e];
            const float2 v = *(const float2*)(node_emb + (size_t)n * H + 2 * tt);
            *(unsigned int*)&ein[e * LDE + half * 256 + 2 * tt] = pack2(v.x, v.y);
        }
        #pragma unroll
        for (int i = tid; i < EPB * 32; i += 256) {
            const int e = i >> 5, j = i & 31;
            const float2 v = *(const float2*)(type_emb + (size_t)tidx[e] * TYPE_DIM + 2 * j);
            *(unsigned int*)&ein[e * LDE + 512 + 2 * j] = pack2(v.x, v.y);
        }
    }
    __syncthreads();

    f32x4 acc[2][4];
    #pragma unroll
    for (int mt = 0; mt < 2; mt++)
        #pragma unroll
        for (int nt = 0; nt < 4; nt++)
            acc[mt][nt] = (f32x4){0.f, 0.f, 0.f, 0.f};

    const int colbase = w * 64;
    const unsigned short* A0 = &ein[l15 * LDE + l4 * 8];
    const unsigned short* A1 = &ein[(16 + l15) * LDE + l4 * 8];
    const unsigned short* B0 = WE + (size_t)(colbase + l15) * KE + l4 * 8;
    const unsigned short* B1 = B0 + 16 * KE;
    const unsigned short* B2 = B0 + 32 * KE;
    const unsigned short* B3 = B0 + 48 * KE;

    for (int ks = 0; ks < KE / 32; ks++) {
        const int o = ks * 32;
        bf16x8 a0 = __builtin_bit_cast(bf16x8, *(const uint4*)(A0 + o));
        bf16x8 a1 = __builtin_bit_cast(bf16x8, *(const uint4*)(A1 + o));
        bf16x8 b0 = __builtin_bit_cast(bf16x8, *(const uint4*)(B0 + o));
        bf16x8 b1 = __builtin_bit_cast(bf16x8, *(const uint4*)(B1 + o));
        bf16x8 b2 = __builtin_bit_cast(bf16x8, *(const uint4*)(B2 + o));
        bf16x8 b3 = __builtin_bit_cast(bf16x8, *(const uint4*)(B3 + o));
        acc[0][0] = __builtin_amdgcn_mfma_f32_16x16x32_bf16(a0, b0, acc[0][0], 0, 0, 0);
        acc[0][1] = __builtin_amdgcn_mfma_f32_16x16x32_bf16(a0, b1, acc[0][1], 0, 0, 0);
        acc[0][2] = __builtin_amdgcn_mfma_f32_16x16x32_bf16(a0, b2, acc[0][2], 0, 0, 0);
        acc[0][3] = __builtin_amdgcn_mfma_f32_16x16x32_bf16(a0, b3, acc[0][3], 0, 0, 0);
        acc[1][0] = __builtin_amdgcn_mfma_f32_16x16x32_bf16(a1, b0, acc[1][0], 0, 0, 0);
        acc[1][1] = __builtin_amdgcn_mfma_f32_16x16x32_bf16(a1, b1, acc[1][1], 0, 0, 0);
        acc[1][2] = __builtin_amdgcn_mfma_f32_16x16x32_bf16(a1, b2, acc[1][2], 0, 0, 0);
        acc[1][3] = __builtin_amdgcn_mfma_f32_16x16x32_bf16(a1, b3, acc[1][3], 0, 0, 0);
    }

    __syncthreads();
    float* fout = (float*)&ein[0];

    float bias[4];
    #pragma unroll
    for (int nt = 0; nt < 4; nt++) bias[nt] = b_edge[colbase + nt * 16 + l15];
    #pragma unroll
    for (int mt = 0; mt < 2; mt++)
        #pragma unroll
        for (int nt = 0; nt < 4; nt++)
            #pragma unroll
            for (int r = 0; r < 4; r++) {
                int row = mt * 16 + l4 * 4 + r;
                fout[row * LDF + colbase + nt * 16 + l15] = acc[mt][nt][r] + bias[nt];
            }
    __syncthreads();

    const float4 gv = *(const float4*)(ln_g + 4 * lane);
    const float4 bv = *(const float4*)(ln_b + 4 * lane);
    for (int rr = 0; rr < 8; rr++) {
        const int row = w * 8 + rr;
        f32x4 v = *(const f32x4*)&fout[row * LDF + 4 * lane];
        float s1 = v[0] + v[1] + v[2] + v[3];
        float s2 = v[0] * v[0] + v[1] * v[1] + v[2] * v[2] + v[3] * v[3];
        #pragma unroll
        for (int o = 32; o > 0; o >>= 1) {
            s1 += __shfl_down(s1, o, 64);
            s2 += __shfl_down(s2, o, 64);
        }
        const float m = __shfl(s1, 0, 64) * (1.0f / (float)H);
        const float q = __shfl(s2, 0, 64) * (1.0f / (float)H);
        const float is = rsqrtf(fmaxf(q - m * m, 0.0f) + 1e-5f);
        float y0 = fmaxf((v[0] - m) * is * gv.x + bv.x, 0.0f);
        float y1 = fmaxf((v[1] - m) * is * gv.y + bv.y, 0.0f);
        float y2 = fmaxf((v[2] - m) * is * gv.z + bv.z, 0.0f);
        float y3 = fmaxf((v[3] - m) * is * gv.w + bv.w, 0.0f);
        __half2 h01 = __floats2half2_rn(y0, y1);
        __half2 h23 = __floats2half2_rn(y2, y3);
        unsigned char* dp = aggb + (size_t)didx[row] * 1024 + lane * 8;
        atomic_pk_f16(dp,     __builtin_bit_cast(unsigned int, h01));
        atomic_pk_f16(dp + 4, __builtin_bit_cast(unsigned int, h23));
    }
    if (tid < EPB) {
        int d = didx[tid];
        atomicAdd(&cntw[d >> 2], 1u << ((d & 3) * 8));
    }
}

// ---------------- node phase: swizzled LDS, merged GRU accs, hp prefetch ---
template<bool SHH>
__global__ __launch_bounds__(1024, 4) void node_mfma(
    const float* __restrict__ node_emb, const float* __restrict__ h_prev,
    const unsigned short* __restrict__ WG, const float* __restrict__ b_gate,
    const float* __restrict__ lng_g, const float* __restrict__ lng_b,
    const unsigned short* __restrict__ WTih, const unsigned short* __restrict__ WThh,
    const float* __restrict__ Whh_f32,
    const float* __restrict__ b_ih, const float* __restrict__ b_hh,
    const float* __restrict__ lnr_g, const float* __restrict__ lnr_b,
    const unsigned int* __restrict__ cntw,
    float* __restrict__ out) {   // out row slots hold fp16 agg (first 512 B)
    // Aga: [64][512] bf16 (x||en, stride 1024B, XOR-swizzled); reused as f32 h[64][256]
    __shared__ __align__(16) unsigned short Aga[NPB * 512];  // 65536 B
    // shr: [64][256] bf16 (u, then hp; stride 512B, XOR-swizzled)
    __shared__ __align__(16) unsigned short shr[NPB * 256];  // 32768 B
    __shared__ float rc[NPB];

    const int tid = threadIdx.x;
    const int n0 = blockIdx.x * NPB;
    const int lane = tid & 63;
    const int w = tid >> 6;          // 0..15, wave w owns cols [w*16, w*16+16)
    const int l15 = lane & 15, l4 = lane >> 4;
    char* AgaB = (char*)Aga;
    char* shrB = (char*)shr;

    if (tid < NPB) {
        int n = n0 + tid;
        float c = 1.0f;
        if (n < N_ENTS) {
            unsigned int cw = cntw[n >> 2];
            c = (float)((cw >> ((n & 3) * 8)) & 0xFFu);
        }
        rc[tid] = 1.0f / fmaxf(c, 1.0f);
    }
    __syncthreads();

    const unsigned char* aggb = (const unsigned char*)out;

    // ---- stage xn|en (Aga), float4-vectorized, swizzled ----
    #pragma unroll
    for (int j = 0; j < 4; j++) {
        int i = tid + j * 1024;               // 0..4095
        int row = i >> 6, c4 = (i & 63) * 4;  // c4: f32-col 0..252
        int nr = n0 + row;
        size_t gn = (size_t)(nr < N_ENTS ? nr : 0);
        float4 xv = *(const float4*)(node_emb + gn * H + c4);
        uint2 eu = *(const uint2*)(aggb + gn * 1024 + c4 * 2);
        float2 e01 = __half22float2(__builtin_bit_cast(__half2, eu.x));
        float2 e23 = __half22float2(__builtin_bit_cast(__half2, eu.y));
        float r = rc[row];
        int swz = (row & 7) << 4;
        uint2 xp, ep;
        xp.x = pack2(xv.x, xv.y); xp.y = pack2(xv.z, xv.w);
        ep.x = pack2(e01.x * r, e01.y * r); ep.y = pack2(e23.x * r, e23.y * r);
        *(uint2*)(AgaB + ((row * 1024 + c4 * 2) ^ swz)) = xp;
        *(uint2*)(AgaB + ((row * 1024 + 512 + c4 * 2) ^ swz)) = ep;
    }

    // ---- prefetch hp into registers (written to shr after u is consumed) ----
    float4 hpre[4];
    #pragma unroll
    for (int j = 0; j < 4; j++) {
        int i = tid + j * 1024;
        int row = i >> 6, c4 = (i & 63) * 4;
        int nr = n0 + row;
        hpre[j] = *(const float4*)(h_prev + (size_t)(nr < N_ENTS ? nr : 0) * H + c4);
    }
    __syncthreads();

    // ---- gate GEMM: u[64x256] = [xn|en] @ W_gate, K=512; 16 cols/wave ----
    {
        f32x4 acc[4];
        #pragma unroll
        for (int m = 0; m < 4; m++) acc[m] = (f32x4){0.f, 0.f, 0.f, 0.f};
        const unsigned short* B0 = WG + (size_t)(w * 16 + l15) * (2 * H) + l4 * 8;
        #pragma unroll 4
        for (int ks = 0; ks < 16; ks++) {
            bf16x8 b0 = __builtin_bit_cast(bf16x8, *(const uint4*)(B0 + ks * 32));
            const int kb = ks * 64 + l4 * 16;
            #pragma unroll
            for (int m = 0; m < 4; m++) {
                bf16x8 a = ldsA(AgaB, m * 16 + l15, kb, 1024);
                acc[m] = __builtin_amdgcn_mfma_f32_16x16x32_bf16(a, b0, acc[m], 0, 0, 0);
            }
        }
        const float bg0 = b_gate[w * 16 + l15];
        #pragma unroll
        for (int m = 0; m < 4; m++)
            #pragma unroll
            for (int r = 0; r < 4; r++) {
                int row = m * 16 + l4 * 4 + r;
                *(unsigned short*)(shrB + ((row * 512 + (w * 16 + l15) * 2) ^ ((row & 7) << 4)))
                    = f2b(acc[m][r] + bg0);
            }
    }
    __syncthreads();

    // ---- gate epilogue: LN(u) -> sigmoid -> fused -> x; 4 rows/wave ----
    {
        const float4 g4 = *(const float4*)(lng_g + 4 * lane);
        const float4 b4 = *(const float4*)(lng_b + 4 * lane);
        for (int rr = 0; rr < 4; rr++) {
            const int row = w * 4 + rr;
            const int swz = (row & 7) << 4;
            short4 us = *(const short4*)(shrB + ((row * 512 + lane * 8) ^ swz));
            float u0 = u2f((unsigned short)us.x), u1 = u2f((unsigned short)us.y);
            float u2 = u2f((unsigned short)us.z), u3 = u2f((unsigned short)us.w);
            float s1 = u0 + u1 + u2 + u3;
            float s2 = u0 * u0 + u1 * u1 + u2 * u2 + u3 * u3;
            #pragma unroll
            for (int o = 32; o > 0; o >>= 1) {
                s1 += __shfl_down(s1, o, 64);
                s2 += __shfl_down(s2, o, 64);
            }
            const float m = __shfl(s1, 0, 64) * (1.0f / (float)H);
            const float q = __shfl(s2, 0, 64) * (1.0f / (float)H);
            const float is = rsqrtf(fmaxf(q - m * m, 0.0f) + 1e-5f);
            short4 xr = *(const short4*)(AgaB + ((row * 1024 + lane * 8) ^ swz));
            short4 er = *(const short4*)(AgaB + ((row * 1024 + 512 + lane * 8) ^ swz));
            float xv[4] = {u2f((unsigned short)xr.x), u2f((unsigned short)xr.y),
                           u2f((unsigned short)xr.z), u2f((unsigned short)xr.w)};
            float ev[4] = {u2f((unsigned short)er.x), u2f((unsigned short)er.y),
                           u2f((unsigned short)er.z), u2f((unsigned short)er.w)};
            float uu[4] = {u0, u1, u2, u3};
            float gl[4] = {g4.x, g4.y, g4.z, g4.w};
            float bl[4] = {b4.x, b4.y, b4.z, b4.w};
            unsigned short xs[4];
            #pragma unroll
            for (int j = 0; j < 4; j++) {
                float gate = sigm((uu[j] - m) * is * gl[j] + bl[j]);
                float fused = gate * xv[j] + (1.0f - gate) * ev[j];
                xs[j] = f2b(0.2f * xv[j] + 0.8f * fused);
            }
            uint2 xp;
            xp.x = (unsigned int)xs[0] | ((unsigned int)xs[1] << 16);
            xp.y = (unsigned int)xs[2] | ((unsigned int)xs[3] << 16);
            *(uint2*)(AgaB + ((row * 1024 + lane * 8) ^ swz)) = xp;
        }
    }
    __syncthreads();

    // ---- write prefetched hp into shr (u dead), swizzled ----
    #pragma unroll
    for (int j = 0; j < 4; j++) {
        int i = tid + j * 1024;
        int row = i >> 6, c4 = (i & 63) * 4;
        int swz = (row & 7) << 4;
        uint2 hp2;
        hp2.x = pack2(hpre[j].x, hpre[j].y);
        hp2.y = pack2(hpre[j].z, hpre[j].w);
        *(uint2*)(shrB + ((row * 512 + c4 * 2) ^ swz)) = hp2;
    }
    __syncthreads();

    // ---- GRU: pass1 r,z with MERGED gi+gh accumulators; pass2 n ----
    const int cl = w * 16 + l15;     // output col in [0,256)

    float rg[4][4], zg[4][4];
    {
        f32x4 ar[4], az[4];
        #pragma unroll
        for (int m = 0; m < 4; m++) {
            ar[m] = (f32x4){0.f, 0.f, 0.f, 0.f};
            az[m] = (f32x4){0.f, 0.f, 0.f, 0.f};
        }
        const unsigned short* bi0 = WTih + (size_t)(cl) * H + l4 * 8;
        const unsigned short* bi1 = WTih + (size_t)(H + cl) * H + l4 * 8;
        const unsigned short* bh0s = WThh + (size_t)(cl) * H + l4 * 8;
        const unsigned short* bh1s = WThh + (size_t)(H + cl) * H + l4 * 8;
        const float* fh0 = Whh_f32 + (size_t)(cl) * H + l4 * 8;
        const float* fh1 = Whh_f32 + (size_t)(H + cl) * H + l4 * 8;
        #pragma unroll 4
        for (int ks = 0; ks < 8; ks++) {
            const int o = ks * 32;
            const int kb = ks * 64 + l4 * 16;
            bf16x8 vI0 = __builtin_bit_cast(bf16x8, *(const uint4*)(bi0 + o));
            bf16x8 vI1 = __builtin_bit_cast(bf16x8, *(const uint4*)(bi1 + o));
            bf16x8 vH0, vH1;
            if (SHH) {
                vH0 = __builtin_bit_cast(bf16x8, *(const uint4*)(bh0s + o));
                vH1 = __builtin_bit_cast(bf16x8, *(const uint4*)(bh1s + o));
            } else {
                vH0 = cvt8(fh0 + o);
                vH1 = cvt8(fh1 + o);
            }
            #pragma unroll
            for (int m = 0; m < 4; m++) {
                const int rw = m * 16 + l15;
                bf16x8 ax = ldsA(AgaB, rw, kb, 1024);
                bf16x8 ah = ldsA(shrB, rw, kb, 512);
                ar[m] = __builtin_amdgcn_mfma_f32_16x16x32_bf16(ax, vI0, ar[m], 0, 0, 0);
                ar[m] = __builtin_amdgcn_mfma_f32_16x16x32_bf16(ah, vH0, ar[m], 0, 0, 0);
                az[m] = __builtin_amdgcn_mfma_f32_16x16x32_bf16(ax, vI1, az[m], 0, 0, 0);
                az[m] = __builtin_amdgcn_mfma_f32_16x16x32_bf16(ah, vH1, az[m], 0, 0, 0);
            }
        }
        const float bi_0 = b_ih[cl], bi_1 = b_ih[H + cl];
        const float bh_0 = b_hh[cl], bh_1 = b_hh[H + cl];
        #pragma unroll
        for (int m = 0; m < 4; m++)
            #pragma unroll
            for (int r = 0; r < 4; r++) {
                rg[m][r] = sigm(ar[m][r] + bi_0 + bh_0);
                zg[m][r] = sigm(az[m][r] + bi_1 + bh_1);
            }
    }

    float hreg[4][4];
    {
        f32x4 aIn[4], aHn[4];
        #pragma unroll
        for (int m = 0; m < 4; m++) {
            aIn[m] = (f32x4){0.f, 0.f, 0.f, 0.f};
            aHn[m] = (f32x4){0.f, 0.f, 0.f, 0.f};
        }
        const unsigned short* bi2 = WTih + (size_t)(2 * H + cl) * H + l4 * 8;
        const unsigned short* bh2s = WThh + (size_t)(2 * H + cl) * H + l4 * 8;
        const float* fh2 = Whh_f32 + (size_t)(2 * H + cl) * H + l4 * 8;
        #pragma unroll 4
        for (int ks = 0; ks < 8; ks++) {
            const int o = ks * 32;
            const int kb = ks * 64 + l4 * 16;
            bf16x8 vI2 = __builtin_bit_cast(bf16x8, *(const uint4*)(bi2 + o));
            bf16x8 vH2;
            if (SHH) vH2 = __builtin_bit_cast(bf16x8, *(const uint4*)(bh2s + o));
            else     vH2 = cvt8(fh2 + o);
            #pragma unroll
            for (int m = 0; m < 4; m++) {
                const int rw = m * 16 + l15;
                bf16x8 ax = ldsA(AgaB, rw, kb, 1024);
                bf16x8 ah = ldsA(shrB, rw, kb, 512);
                aIn[m] = __builtin_amdgcn_mfma_f32_16x16x32_bf16(ax, vI2, aIn[m], 0, 0, 0);
                aHn[m] = __builtin_amdgcn_mfma_f32_16x16x32_bf16(ah, vH2, aHn[m], 0, 0, 0);
            }
        }
        const float bi_2 = b_ih[2 * H + cl];
        const float bh_2 = b_hh[2 * H + cl];
        #pragma unroll
        for (int m = 0; m < 4; m++)
            #pragma unroll
            for (int r = 0; r < 4; r++) {
                const int row = m * 16 + l4 * 4 + r;
                int nr = n0 + row; if (nr >= N_ENTS) nr = N_ENTS - 1;
                float nn = tanhf(aIn[m][r] + bi_2 + rg[m][r] * (aHn[m][r] + bh_2));
                float hpv = h_prev[(size_t)nr * H + cl];
                hreg[m][r] = (1.0f - zg[m][r]) * nn + zg[m][r] * hpv;
            }
    }
    __syncthreads();   // Aga dead -> reuse as f32 h[64][256], swizzled

    float* hb = (float*)&Aga[0];
    (void)hb;
    #pragma unroll
    for (int m = 0; m < 4; m++)
        #pragma unroll
        for (int r = 0; r < 4; r++) {
            const int row = m * 16 + l4 * 4 + r;
            *(float*)(AgaB + ((row * 1024 + cl * 4) ^ ((row & 7) << 4))) = hreg[m][r];
        }
    __syncthreads();

    // ---- final LN + 0.3*h_prev residual; 4 rows/wave ----
    {
        const float4 g4 = *(const float4*)(lnr_g + 4 * lane);
        const float4 b4 = *(const float4*)(lnr_b + 4 * lane);
        for (int rr = 0; rr < 4; rr++) {
            const int row = w * 4 + rr;
            const int nr = n0 + row;
            f32x4 hv = *(const f32x4*)(AgaB + ((row * 1024 + lane * 16) ^ ((row & 7) << 4)));
            float s1 = hv[0] + hv[1] + hv[2] + hv[3];
            float s2 = hv[0] * hv[0] + hv[1] * hv[1] + hv[2] * hv[2] + hv[3] * hv[3];
            #pragma unroll
            for (int o = 32; o > 0; o >>= 1) {
                s1 += __shfl_down(s1, o, 64);
                s2 += __shfl_down(s2, o, 64);
            }
            const float m = __shfl(s1, 0, 64) * (1.0f / (float)H);
            const float q = __shfl(s2, 0, 64) * (1.0f / (float)H);
            const float is = rsqrtf(fmaxf(q - m * m, 0.0f) + 1e-5f);
            if (nr < N_ENTS) {
                const float4 hp4 = *(const float4*)(h_prev + (size_t)nr * H + 4 * lane);
                float4 o4;
                o4.x = (hv[0] - m) * is * g4.x + b4.x + 0.3f * hp4.x;
                o4.y = (hv[1] - m) * is * g4.y + b4.y + 0.3f * hp4.y;
                o4.z = (hv[2] - m) * is * g4.z + b4.z + 0.3f * hp4.z;
                o4.w = (hv[3] - m) * is * g4.w + b4.w + 0.3f * hp4.w;
                *(float4*)(out + (size_t)nr * H + 4 * lane) = o4;
            }
        }
    }
}

extern "C" void kernel_launch(void* const* d_in, const int* in_sizes, int n_in,
                              void* d_out, int out_size, void* d_ws, size_t ws_size,
                              hipStream_t stream) {
    (void)in_sizes; (void)n_in; (void)out_size;
    const float* node_emb  = (const float*)d_in[0];
    const float* h_prev    = (const float*)d_in[1];
    const float* type_emb  = (const float*)d_in[2];
    const float* W_edge    = (const float*)d_in[3];
    const float* b_edge    = (const float*)d_in[4];
    const float* ln_edge_g = (const float*)d_in[5];
    const float* ln_edge_b = (const float*)d_in[6];
    const float* W_gate    = (const float*)d_in[7];
    const float* b_gate    = (const float*)d_in[8];
    const float* ln_gate_g = (const float*)d_in[9];
    const float* ln_gate_b = (const float*)d_in[10];
    const float* W_ih      = (const float*)d_in[11];
    const float* W_hh      = (const float*)d_in[12];
    const float* b_ih      = (const float*)d_in[13];
    const float* b_hh      = (const float*)d_in[14];
    const float* ln_gru_g  = (const float*)d_in[15];
    const float* ln_gru_b  = (const float*)d_in[16];
    const int*   src       = (const int*)d_in[17];
    const int*   dst       = (const int*)d_in[18];
    const int*   et        = (const int*)d_in[19];
    float* out = (float*)d_out;

    // workspace layout:
    //   [0, 100000)         cnt u8-packed, 4/word
    //   [100000, 394912)    WE bf16 256x576   (edge phase only)
    //   [100000, 362144)    WG bf16 256x512   (node phase; overwrites WE)
    //   [362144, 755360)    WTih bf16 768x256 (node phase)
    //   [755360, 1148576)   WThh bf16 768x256 (only if ws_size allows)
    char* ws = (char*)d_ws;
    unsigned int* cntw  = (unsigned int*)ws;
    unsigned short* WE   = (unsigned short*)(ws + 100000);
    unsigned short* WG   = (unsigned short*)(ws + 100000);
    unsigned short* WTih = (unsigned short*)(ws + 362144);
    unsigned short* WThh = (unsigned short*)(ws + 755360);
    const bool big = ws_size >= (size_t)1148576;

    hipMemsetAsync(cntw, 0, 100000, stream);
    hipMemsetAsync(out, 0, (size_t)N_ENTS * H * sizeof(float), stream);

    hipLaunchKernelGGL(transpose_we, dim3(256), dim3(256), 0, stream, W_edge, WE);

    hipLaunchKernelGGL(edge_mfma, dim3(N_EDGES / EPB), dim3(256), 0, stream,
                       node_emb, type_emb, WE, b_edge, ln_edge_g, ln_edge_b,
                       src, dst, et, (unsigned char*)out, cntw);

    hipLaunchKernelGGL(transpose_wg, dim3(256), dim3(256), 0, stream, W_gate, WG);
    hipLaunchKernelGGL(cast_gru, dim3(768), dim3(256), 0, stream,
                       W_ih, W_hh, WTih, WThh, big ? 1 : 0);

    const int nblocks = (N_ENTS + NPB - 1) / NPB;
    if (big) {
        hipLaunchKernelGGL((node_mfma<true>), dim3(nblocks), dim3(1024), 0, stream,
                           node_emb, h_prev, WG, b_gate, ln_gate_g, ln_gate_b,
                           WTih, WThh, W_hh, b_ih, b_hh, ln_gru_g, ln_gru_b,
                           cntw, out);
    } else {
        hipLaunchKernelGGL((node_mfma<false>), dim3(nblocks), dim3(1024), 0, stream,
                           node_emb, h_prev, WG, b_gate, ln_gate_g, ln_gate_b,
                           WTih, WTih /*unused*/, W_hh, b_ih, b_hh, ln_gru_g, ln_gru_b,
                           cntw, out);
    }
}